// Round 1
// baseline (3452.019 us; speedup 1.0000x reference)
//
#include <hip/hip_runtime.h>

#define N_USERS 200000
#define N_ITEMS 50000
#define NTOT    250000
#define NNZ     5000000
#define EMB     64
#define BATCH   16384

// cur = concat(user_emb, item_emb), float4 copies
__global__ void init_cur_kernel(const float* __restrict__ ue,
                                const float* __restrict__ ie,
                                float* __restrict__ cur) {
    long i = (long)blockIdx.x * blockDim.x + threadIdx.x;   // float4 index
    const long n_u4 = (long)N_USERS * EMB / 4;              // 3.2M
    const long n_t4 = (long)NTOT * EMB / 4;                 // 4.0M
    if (i < n_u4) {
        ((float4*)cur)[i] = ((const float4*)ue)[i];
    } else if (i < n_t4) {
        ((float4*)cur)[i] = ((const float4*)ie)[i - n_u4];
    }
}

// one wavefront per nonzero: next[row][:] += val * cur[col][:]
__global__ void spmm_atomic_kernel(const int* __restrict__ rows,
                                   const int* __restrict__ cols,
                                   const float* __restrict__ vals,
                                   const float* __restrict__ cur,
                                   float* __restrict__ next) {
    int t    = blockIdx.x * blockDim.x + threadIdx.x;
    int nz   = t >> 6;          // wave id = nonzero id
    int lane = t & 63;
    if (nz >= NNZ) return;
    int   r = rows[nz];
    int   c = cols[nz];
    float v = vals[nz];
    float x = cur[(long)c * EMB + lane];
    atomicAdd(&next[(long)r * EMB + lane], v * x);
}

// u_buf[b][:] += src[batch[b,0]][:] ; it_buf[b][:] += src[N_USERS+batch[b,1]][:]
__global__ void gather_add_kernel(const float* __restrict__ src,
                                  const int* __restrict__ batch,
                                  float* __restrict__ ub,
                                  float* __restrict__ ib) {
    int t    = blockIdx.x * blockDim.x + threadIdx.x;
    int b    = t >> 6;
    int lane = t & 63;
    if (b >= BATCH) return;
    int ur = batch[2 * b];
    int ir = N_USERS + batch[2 * b + 1];
    ub[(long)b * EMB + lane] += src[(long)ur * EMB + lane];
    ib[(long)b * EMB + lane] += src[(long)ir * EMB + lane];
}

// out[b] = dot(u_buf[b], it_buf[b]) / 16   (the /4 per side of e = acc/4)
__global__ void dot_kernel(const float* __restrict__ ub,
                           const float* __restrict__ ib,
                           float* __restrict__ out) {
    int t    = blockIdx.x * blockDim.x + threadIdx.x;
    int b    = t >> 6;
    int lane = t & 63;
    if (b >= BATCH) return;
    float p = ub[(long)b * EMB + lane] * ib[(long)b * EMB + lane];
    #pragma unroll
    for (int off = 32; off > 0; off >>= 1)
        p += __shfl_down(p, off, 64);
    if (lane == 0) out[b] = p * (1.0f / 16.0f);
}

extern "C" void kernel_launch(void* const* d_in, const int* in_sizes, int n_in,
                              void* d_out, int out_size, void* d_ws, size_t ws_size,
                              hipStream_t stream) {
    const float* ue    = (const float*)d_in[0];   // (200000,64) f32
    const float* ie    = (const float*)d_in[1];   // (50000,64)  f32
    const int*   rows  = (const int*)d_in[2];     // (5M,) i32
    const int*   cols  = (const int*)d_in[3];     // (5M,) i32
    const float* vals  = (const float*)d_in[4];   // (5M,) f32
    const int*   batch = (const int*)d_in[5];     // (16384,2) i32
    float*       out   = (float*)d_out;           // (16384,) f32

    const size_t EMB_BYTES = (size_t)NTOT * EMB * sizeof(float);   // 64,000,000
    const size_t BUF_BYTES = (size_t)BATCH * EMB * sizeof(float);  // 4,194,304
    char* ws  = (char*)d_ws;
    float* cur = (float*)(ws);
    float* nxt = (float*)(ws + EMB_BYTES);
    float* ub  = (float*)(ws + 2 * EMB_BYTES);
    float* ib  = (float*)(ws + 2 * EMB_BYTES + BUF_BYTES);

    // 1) cur = emb
    {
        int n_t4 = NTOT * (EMB / 4);              // 4,000,000 threads
        init_cur_kernel<<<(n_t4 + 255) / 256, 256, 0, stream>>>(ue, ie, cur);
    }
    // 2) acc-at-batch-rows buffers start at emb contribution
    hipMemsetAsync(ub, 0, 2 * BUF_BYTES, stream);   // ub, ib contiguous
    gather_add_kernel<<<(BATCH * 64) / 256, 256, 0, stream>>>(cur, batch, ub, ib);

    // 3) three propagation layers
    for (int l = 0; l < 3; ++l) {
        hipMemsetAsync(nxt, 0, EMB_BYTES, stream);
        spmm_atomic_kernel<<<NNZ / 4, 256, 0, stream>>>(rows, cols, vals, cur, nxt);
        gather_add_kernel<<<(BATCH * 64) / 256, 256, 0, stream>>>(nxt, batch, ub, ib);
        float* tmp = cur; cur = nxt; nxt = tmp;
    }

    // 4) score
    dot_kernel<<<(BATCH * 64) / 256, 256, 0, stream>>>(ub, ib, out);
}

// Round 2
// 1519.775 us; speedup vs baseline: 2.2714x; 2.2714x over previous
//
#include <hip/hip_runtime.h>

#define N_USERS 200000
#define N_ITEMS 50000
#define NTOT    250000
#define NNZ     5000000
#define EMB     64
#define BATCH   16384

#define SCAN_ELEMS 1024
#define NBLK_SCAN ((NTOT + SCAN_ELEMS - 1) / SCAN_ELEMS)   // 245

// ---------------- common kernels ----------------

__global__ void init_cur_kernel(const float* __restrict__ ue,
                                const float* __restrict__ ie,
                                float* __restrict__ cur) {
    long i = (long)blockIdx.x * blockDim.x + threadIdx.x;   // float4 index
    const long n_u4 = (long)N_USERS * EMB / 4;              // 3.2M
    const long n_t4 = (long)NTOT * EMB / 4;                 // 4.0M
    if (i < n_u4) {
        ((float4*)cur)[i] = ((const float4*)ue)[i];
    } else if (i < n_t4) {
        ((float4*)cur)[i] = ((const float4*)ie)[i - n_u4];
    }
}

__global__ void gather_add_kernel(const float* __restrict__ src,
                                  const int* __restrict__ batch,
                                  float* __restrict__ ub,
                                  float* __restrict__ ib) {
    int t    = blockIdx.x * blockDim.x + threadIdx.x;
    int b    = t >> 6;
    int lane = t & 63;
    if (b >= BATCH) return;
    int ur = batch[2 * b];
    int ir = N_USERS + batch[2 * b + 1];
    ub[(long)b * EMB + lane] += src[(long)ur * EMB + lane];
    ib[(long)b * EMB + lane] += src[(long)ir * EMB + lane];
}

__global__ void dot_kernel(const float* __restrict__ ub,
                           const float* __restrict__ ib,
                           float* __restrict__ out) {
    int t    = blockIdx.x * blockDim.x + threadIdx.x;
    int b    = t >> 6;
    int lane = t & 63;
    if (b >= BATCH) return;
    float p = ub[(long)b * EMB + lane] * ib[(long)b * EMB + lane];
    #pragma unroll
    for (int off = 32; off > 0; off >>= 1)
        p += __shfl_down(p, off, 64);
    if (lane == 0) out[b] = p * (1.0f / 16.0f);
}

// ---------------- CSR build ----------------

__global__ void hist_kernel(const int* __restrict__ rows, int* __restrict__ counts) {
    int stride = gridDim.x * blockDim.x;
    for (int i = blockIdx.x * blockDim.x + threadIdx.x; i < NNZ; i += stride)
        atomicAdd(&counts[rows[i]], 1);
}

__global__ void reduce_counts_kernel(const int* __restrict__ counts, int* __restrict__ bsum) {
    __shared__ int s[256];
    int b = blockIdx.x, t = threadIdx.x;
    int base = b * SCAN_ELEMS + t * 4;
    int sum = 0;
    #pragma unroll
    for (int k = 0; k < 4; ++k) {
        int idx = base + k;
        if (idx < NTOT) sum += counts[idx];
    }
    s[t] = sum;
    __syncthreads();
    for (int off = 128; off > 0; off >>= 1) {
        if (t < off) s[t] += s[t + off];
        __syncthreads();
    }
    if (t == 0) bsum[b] = s[0];
}

__global__ void scan_bsums_kernel(const int* __restrict__ bsum, int* __restrict__ bofs) {
    __shared__ int s[256];
    int t = threadIdx.x;
    s[t] = (t < NBLK_SCAN) ? bsum[t] : 0;
    __syncthreads();
    for (int off = 1; off < 256; off <<= 1) {
        int x = s[t];
        int y = (t >= off) ? s[t - off] : 0;
        __syncthreads();
        s[t] = x + y;
        __syncthreads();
    }
    if (t < NBLK_SCAN) bofs[t] = (t == 0) ? 0 : s[t - 1];
}

__global__ void scan_counts_kernel(const int* __restrict__ counts,
                                   const int* __restrict__ bofs,
                                   int* __restrict__ rowptr,
                                   int* __restrict__ wofs) {
    __shared__ int s[256];
    int b = blockIdx.x, t = threadIdx.x;
    int base = b * SCAN_ELEMS + t * 4;
    int c[4];
    int tsum = 0;
    #pragma unroll
    for (int k = 0; k < 4; ++k) {
        int idx = base + k;
        c[k] = (idx < NTOT) ? counts[idx] : 0;
        tsum += c[k];
    }
    s[t] = tsum;
    __syncthreads();
    for (int off = 1; off < 256; off <<= 1) {
        int x = s[t];
        int y = (t >= off) ? s[t - off] : 0;
        __syncthreads();
        s[t] = x + y;
        __syncthreads();
    }
    int excl = (t == 0) ? 0 : s[t - 1];
    int run = bofs[b] + excl;
    #pragma unroll
    for (int k = 0; k < 4; ++k) {
        int idx = base + k;
        if (idx < NTOT) { rowptr[idx] = run; wofs[idx] = run; run += c[k]; }
    }
    if (b == 0 && t == 0) rowptr[NTOT] = NNZ;
}

__global__ void scatter_kernel(const int* __restrict__ rows,
                               const int* __restrict__ cols,
                               const float* __restrict__ vals,
                               int* __restrict__ wofs,
                               int2* __restrict__ packed) {
    int stride = gridDim.x * blockDim.x;
    for (int i = blockIdx.x * blockDim.x + threadIdx.x; i < NNZ; i += stride) {
        int r = rows[i];
        int pos = atomicAdd(&wofs[r], 1);
        packed[pos] = make_int2(cols[i], __float_as_int(vals[i]));
    }
}

// ---------------- CSR SpMM: one wave per row, lane = emb dim ----------------

__global__ void spmm_csr_kernel(const int* __restrict__ rowptr,
                                const int2* __restrict__ packed,
                                const float* __restrict__ cur,
                                float* __restrict__ next) {
    int t    = blockIdx.x * blockDim.x + threadIdx.x;
    int r    = t >> 6;
    int lane = t & 63;
    if (r >= NTOT) return;
    int s = rowptr[r];
    int e = rowptr[r + 1];
    float acc = 0.0f;
    for (int base = s; base < e; base += 64) {
        int j = base + lane;
        int2 p = (j < e) ? packed[j] : make_int2(0, 0);
        int cnt = e - base;
        if (cnt > 64) cnt = 64;
        for (int k = 0; k < cnt; ++k) {
            int   cc = __shfl(p.x, k, 64);
            float vv = __int_as_float(__shfl(p.y, k, 64));
            acc += vv * cur[(long)cc * EMB + lane];
        }
    }
    next[(long)r * EMB + lane] = acc;
}

// ---------------- fallback atomic SpMM (small-ws path) ----------------

__global__ void spmm_atomic_kernel(const int* __restrict__ rows,
                                   const int* __restrict__ cols,
                                   const float* __restrict__ vals,
                                   const float* __restrict__ cur,
                                   float* __restrict__ next) {
    int t    = blockIdx.x * blockDim.x + threadIdx.x;
    int nz   = t >> 6;
    int lane = t & 63;
    if (nz >= NNZ) return;
    int   r = rows[nz];
    int   c = cols[nz];
    float v = vals[nz];
    float x = cur[(long)c * EMB + lane];
    atomicAdd(&next[(long)r * EMB + lane], v * x);
}

// ---------------- launch ----------------

extern "C" void kernel_launch(void* const* d_in, const int* in_sizes, int n_in,
                              void* d_out, int out_size, void* d_ws, size_t ws_size,
                              hipStream_t stream) {
    const float* ue    = (const float*)d_in[0];
    const float* ie    = (const float*)d_in[1];
    const int*   rows  = (const int*)d_in[2];
    const int*   cols  = (const int*)d_in[3];
    const float* vals  = (const float*)d_in[4];
    const int*   batch = (const int*)d_in[5];
    float*       out   = (float*)d_out;

    const size_t EMB_BYTES = (size_t)NTOT * EMB * sizeof(float);   // 64,000,000
    const size_t BUF_BYTES = (size_t)BATCH * EMB * sizeof(float);  // 4,194,304
    const size_t PCK_BYTES = (size_t)NNZ * sizeof(int2);           // 40,000,000
    const size_t PTR_BYTES = ((size_t)(NTOT + 1) * sizeof(int) + 255) & ~(size_t)255;
    const size_t CNT_BYTES = ((size_t)NTOT * sizeof(int) + 255) & ~(size_t)255;
    const size_t BSM_BYTES = 4096;

    char* ws = (char*)d_ws;
    size_t off = 0;
    float* cur    = (float*)(ws + off); off += EMB_BYTES;
    float* nxt    = (float*)(ws + off); off += EMB_BYTES;
    float* ub     = (float*)(ws + off); off += BUF_BYTES;
    float* ib     = (float*)(ws + off); off += BUF_BYTES;   // ub,ib contiguous
    int2*  packed = (int2*)(ws + off);  off += PCK_BYTES;
    int*   rowptr = (int*)(ws + off);   off += PTR_BYTES;
    int*   wofs   = (int*)(ws + off);   off += CNT_BYTES;
    int*   counts = (int*)(ws + off);   off += CNT_BYTES;
    int*   bsum   = (int*)(ws + off);   off += BSM_BYTES;
    int*   bofs   = (int*)(ws + off);   off += BSM_BYTES;
    const size_t NEEDED_CSR = off;

    // 1) cur = concat(emb)
    {
        int n_t4 = NTOT * (EMB / 4);
        init_cur_kernel<<<(n_t4 + 255) / 256, 256, 0, stream>>>(ue, ie, cur);
    }
    // 2) layer-0 contribution at batch rows
    hipMemsetAsync(ub, 0, 2 * BUF_BYTES, stream);
    gather_add_kernel<<<(BATCH * 64) / 256, 256, 0, stream>>>(cur, batch, ub, ib);

    if (ws_size >= NEEDED_CSR) {
        // 3) build CSR (histogram -> 2-level exclusive scan -> scatter)
        hipMemsetAsync(counts, 0, CNT_BYTES, stream);
        hist_kernel<<<2048, 256, 0, stream>>>(rows, counts);
        reduce_counts_kernel<<<NBLK_SCAN, 256, 0, stream>>>(counts, bsum);
        scan_bsums_kernel<<<1, 256, 0, stream>>>(bsum, bofs);
        scan_counts_kernel<<<NBLK_SCAN, 256, 0, stream>>>(counts, bofs, rowptr, wofs);
        scatter_kernel<<<2048, 256, 0, stream>>>(rows, cols, vals, wofs, packed);

        // 4) three atomic-free propagation layers (full-row write, no memset)
        for (int l = 0; l < 3; ++l) {
            spmm_csr_kernel<<<(NTOT * 64) / 256 + 1, 256, 0, stream>>>(rowptr, packed, cur, nxt);
            gather_add_kernel<<<(BATCH * 64) / 256, 256, 0, stream>>>(nxt, batch, ub, ib);
            float* tmp = cur; cur = nxt; nxt = tmp;
        }
    } else {
        // fallback: R1 atomic path (fits in 136.4 MB)
        for (int l = 0; l < 3; ++l) {
            hipMemsetAsync(nxt, 0, EMB_BYTES, stream);
            spmm_atomic_kernel<<<NNZ / 4, 256, 0, stream>>>(rows, cols, vals, cur, nxt);
            gather_add_kernel<<<(BATCH * 64) / 256, 256, 0, stream>>>(nxt, batch, ub, ib);
            float* tmp = cur; cur = nxt; nxt = tmp;
        }
    }

    // 5) score
    dot_kernel<<<(BATCH * 64) / 256, 256, 0, stream>>>(ub, ib, out);
}

// Round 3
// 1502.074 us; speedup vs baseline: 2.2982x; 1.0118x over previous
//
#include <hip/hip_runtime.h>

#define N_USERS 200000
#define N_ITEMS 50000
#define NTOT    250000
#define NNZ     5000000
#define EMB     64
#define BATCH   16384

#define SCAN_ELEMS 1024
#define NBLK_SCAN ((NTOT + SCAN_ELEMS - 1) / SCAN_ELEMS)   // 245

// ---------------- common kernels ----------------

__global__ void init_cur_kernel(const float* __restrict__ ue,
                                const float* __restrict__ ie,
                                float* __restrict__ cur) {
    long i = (long)blockIdx.x * blockDim.x + threadIdx.x;   // float4 index
    const long n_u4 = (long)N_USERS * EMB / 4;
    const long n_t4 = (long)NTOT * EMB / 4;
    if (i < n_u4) {
        ((float4*)cur)[i] = ((const float4*)ue)[i];
    } else if (i < n_t4) {
        ((float4*)cur)[i] = ((const float4*)ie)[i - n_u4];
    }
}

__global__ void gather_add_kernel(const float* __restrict__ src,
                                  const int* __restrict__ batch,
                                  float* __restrict__ ub,
                                  float* __restrict__ ib) {
    int t    = blockIdx.x * blockDim.x + threadIdx.x;
    int b    = t >> 6;
    int lane = t & 63;
    if (b >= BATCH) return;
    int ur = batch[2 * b];
    int ir = N_USERS + batch[2 * b + 1];
    ub[(long)b * EMB + lane] += src[(long)ur * EMB + lane];
    ib[(long)b * EMB + lane] += src[(long)ir * EMB + lane];
}

__global__ void dot_kernel(const float* __restrict__ ub,
                           const float* __restrict__ ib,
                           float* __restrict__ out) {
    int t    = blockIdx.x * blockDim.x + threadIdx.x;
    int b    = t >> 6;
    int lane = t & 63;
    if (b >= BATCH) return;
    float p = ub[(long)b * EMB + lane] * ib[(long)b * EMB + lane];
    #pragma unroll
    for (int off = 32; off > 0; off >>= 1)
        p += __shfl_down(p, off, 64);
    if (lane == 0) out[b] = p * (1.0f / 16.0f);
}

// ---------------- CSR build ----------------

// histogram + per-nz rank in one pass (rank = order within its row)
__global__ void histrank_kernel(const int* __restrict__ rows,
                                int* __restrict__ counts,
                                int* __restrict__ rank) {
    int i = blockIdx.x * blockDim.x + threadIdx.x;
    if (i >= NNZ) return;
    rank[i] = atomicAdd(&counts[rows[i]], 1);
}

__global__ void reduce_counts_kernel(const int* __restrict__ counts, int* __restrict__ bsum) {
    __shared__ int s[256];
    int b = blockIdx.x, t = threadIdx.x;
    int base = b * SCAN_ELEMS + t * 4;
    int sum = 0;
    #pragma unroll
    for (int k = 0; k < 4; ++k) {
        int idx = base + k;
        if (idx < NTOT) sum += counts[idx];
    }
    s[t] = sum;
    __syncthreads();
    for (int off = 128; off > 0; off >>= 1) {
        if (t < off) s[t] += s[t + off];
        __syncthreads();
    }
    if (t == 0) bsum[b] = s[0];
}

__global__ void scan_bsums_kernel(const int* __restrict__ bsum, int* __restrict__ bofs) {
    __shared__ int s[256];
    int t = threadIdx.x;
    s[t] = (t < NBLK_SCAN) ? bsum[t] : 0;
    __syncthreads();
    for (int off = 1; off < 256; off <<= 1) {
        int x = s[t];
        int y = (t >= off) ? s[t - off] : 0;
        __syncthreads();
        s[t] = x + y;
        __syncthreads();
    }
    if (t < NBLK_SCAN) bofs[t] = (t == 0) ? 0 : s[t - 1];
}

__global__ void scan_counts_kernel(const int* __restrict__ counts,
                                   const int* __restrict__ bofs,
                                   int* __restrict__ rowptr) {
    __shared__ int s[256];
    int b = blockIdx.x, t = threadIdx.x;
    int base = b * SCAN_ELEMS + t * 4;
    int c[4];
    int tsum = 0;
    #pragma unroll
    for (int k = 0; k < 4; ++k) {
        int idx = base + k;
        c[k] = (idx < NTOT) ? counts[idx] : 0;
        tsum += c[k];
    }
    s[t] = tsum;
    __syncthreads();
    for (int off = 1; off < 256; off <<= 1) {
        int x = s[t];
        int y = (t >= off) ? s[t - off] : 0;
        __syncthreads();
        s[t] = x + y;
        __syncthreads();
    }
    int excl = (t == 0) ? 0 : s[t - 1];
    int run = bofs[b] + excl;
    #pragma unroll
    for (int k = 0; k < 4; ++k) {
        int idx = base + k;
        if (idx < NTOT) { rowptr[idx] = run; run += c[k]; }
    }
    if (b == 0 && t == 0) rowptr[NTOT] = NNZ;
}

// two 4B scatter passes: 20MB dirty footprint each -> L2 assembles full lines
__global__ void scatter_col_kernel(const int* __restrict__ rows,
                                   const int* __restrict__ rank,
                                   const int* __restrict__ cols,
                                   const int* __restrict__ rowptr,
                                   int* __restrict__ pcol) {
    int i = blockIdx.x * blockDim.x + threadIdx.x;
    if (i >= NNZ) return;
    pcol[rowptr[rows[i]] + rank[i]] = cols[i];
}

__global__ void scatter_val_kernel(const int* __restrict__ rows,
                                   const int* __restrict__ rank,
                                   const float* __restrict__ vals,
                                   const int* __restrict__ rowptr,
                                   float* __restrict__ pval) {
    int i = blockIdx.x * blockDim.x + threadIdx.x;
    if (i >= NNZ) return;
    pval[rowptr[rows[i]] + rank[i]] = vals[i];
}

// ---------------- CSR SpMM: one wave per row, lane = emb dim ----------------

__global__ void spmm_csr_kernel(const int* __restrict__ rowptr,
                                const int* __restrict__ pcol,
                                const float* __restrict__ pval,
                                const float* __restrict__ cur,
                                float* __restrict__ next) {
    int t    = blockIdx.x * blockDim.x + threadIdx.x;
    int r    = t >> 6;
    int lane = t & 63;
    if (r >= NTOT) return;
    int s = rowptr[r];
    int e = rowptr[r + 1];
    float acc = 0.0f;
    for (int base = s; base < e; base += 64) {
        int j = base + lane;
        int   pc = (j < e) ? pcol[j] : 0;
        float pv = (j < e) ? pval[j] : 0.0f;
        int cnt = e - base;
        if (cnt > 64) cnt = 64;
        for (int k = 0; k < cnt; ++k) {
            int   cc = __shfl(pc, k, 64);
            float vv = __shfl(pv, k, 64);
            acc += vv * cur[(long)cc * EMB + lane];
        }
    }
    next[(long)r * EMB + lane] = acc;
}

// ---------------- fallback atomic SpMM (small-ws path) ----------------

__global__ void spmm_atomic_kernel(const int* __restrict__ rows,
                                   const int* __restrict__ cols,
                                   const float* __restrict__ vals,
                                   const float* __restrict__ cur,
                                   float* __restrict__ next) {
    int t    = blockIdx.x * blockDim.x + threadIdx.x;
    int nz   = t >> 6;
    int lane = t & 63;
    if (nz >= NNZ) return;
    int   r = rows[nz];
    int   c = cols[nz];
    float v = vals[nz];
    float x = cur[(long)c * EMB + lane];
    atomicAdd(&next[(long)r * EMB + lane], v * x);
}

// ---------------- launch ----------------

extern "C" void kernel_launch(void* const* d_in, const int* in_sizes, int n_in,
                              void* d_out, int out_size, void* d_ws, size_t ws_size,
                              hipStream_t stream) {
    const float* ue    = (const float*)d_in[0];
    const float* ie    = (const float*)d_in[1];
    const int*   rows  = (const int*)d_in[2];
    const int*   cols  = (const int*)d_in[3];
    const float* vals  = (const float*)d_in[4];
    const int*   batch = (const int*)d_in[5];
    float*       out   = (float*)d_out;

    const size_t EMB_BYTES = (size_t)NTOT * EMB * sizeof(float);   // 64,000,000
    const size_t BUF_BYTES = (size_t)BATCH * EMB * sizeof(float);  // 4,194,304
    const size_t NZI_BYTES = (size_t)NNZ * sizeof(int);            // 20,000,000
    const size_t PTR_BYTES = ((size_t)(NTOT + 1) * sizeof(int) + 255) & ~(size_t)255;
    const size_t CNT_BYTES = ((size_t)NTOT * sizeof(int) + 255) & ~(size_t)255;
    const size_t BSM_BYTES = 4096;

    char* ws = (char*)d_ws;
    size_t off = 0;
    float* cur    = (float*)(ws + off); off += EMB_BYTES;
    float* nxt    = (float*)(ws + off); off += EMB_BYTES;
    float* ub     = (float*)(ws + off); off += BUF_BYTES;
    float* ib     = (float*)(ws + off); off += BUF_BYTES;   // ub,ib contiguous
    int*   pcol   = (int*)(ws + off);   off += NZI_BYTES;
    float* pval   = (float*)(ws + off); off += NZI_BYTES;
    int*   rank   = (int*)(ws + off);   off += NZI_BYTES;
    int*   rowptr = (int*)(ws + off);   off += PTR_BYTES;
    int*   counts = (int*)(ws + off);   off += CNT_BYTES;
    int*   bsum   = (int*)(ws + off);   off += BSM_BYTES;
    int*   bofs   = (int*)(ws + off);   off += BSM_BYTES;
    const size_t NEEDED_CSR = off;

    // 1) cur = concat(emb)
    {
        int n_t4 = NTOT * (EMB / 4);
        init_cur_kernel<<<(n_t4 + 255) / 256, 256, 0, stream>>>(ue, ie, cur);
    }
    // 2) layer-0 contribution at batch rows
    hipMemsetAsync(ub, 0, 2 * BUF_BYTES, stream);
    gather_add_kernel<<<(BATCH * 64) / 256, 256, 0, stream>>>(cur, batch, ub, ib);

    if (ws_size >= NEEDED_CSR) {
        // 3) build CSR: hist+rank -> 2-level scan -> two 4B scatter passes
        hipMemsetAsync(counts, 0, CNT_BYTES, stream);
        const int NZB = (NNZ + 255) / 256;
        histrank_kernel<<<NZB, 256, 0, stream>>>(rows, counts, rank);
        reduce_counts_kernel<<<NBLK_SCAN, 256, 0, stream>>>(counts, bsum);
        scan_bsums_kernel<<<1, 256, 0, stream>>>(bsum, bofs);
        scan_counts_kernel<<<NBLK_SCAN, 256, 0, stream>>>(counts, bofs, rowptr);
        scatter_col_kernel<<<NZB, 256, 0, stream>>>(rows, rank, cols, rowptr, pcol);
        scatter_val_kernel<<<NZB, 256, 0, stream>>>(rows, rank, vals, rowptr, pval);

        // 4) three atomic-free propagation layers (full-row write, no memset)
        for (int l = 0; l < 3; ++l) {
            spmm_csr_kernel<<<(NTOT * 64) / 256 + 1, 256, 0, stream>>>(rowptr, pcol, pval, cur, nxt);
            gather_add_kernel<<<(BATCH * 64) / 256, 256, 0, stream>>>(nxt, batch, ub, ib);
            float* tmp = cur; cur = nxt; nxt = tmp;
        }
    } else {
        // fallback: atomic path (fits in 136.4 MB)
        for (int l = 0; l < 3; ++l) {
            hipMemsetAsync(nxt, 0, EMB_BYTES, stream);
            spmm_atomic_kernel<<<NNZ / 4, 256, 0, stream>>>(rows, cols, vals, cur, nxt);
            gather_add_kernel<<<(BATCH * 64) / 256, 256, 0, stream>>>(nxt, batch, ub, ib);
            float* tmp = cur; cur = nxt; nxt = tmp;
        }
    }

    // 5) score
    dot_kernel<<<(BATCH * 64) / 256, 256, 0, stream>>>(ub, ib, out);
}

// Round 4
// 1015.931 us; speedup vs baseline: 3.3979x; 1.4785x over previous
//
#include <hip/hip_runtime.h>

#define N_USERS 200000
#define N_ITEMS 50000
#define NTOT    250000
#define NNZ     5000000
#define EMB     64
#define BATCH   16384

#define SCAN_ELEMS 1024
#define NBLK_SCAN ((NTOT + SCAN_ELEMS - 1) / SCAN_ELEMS)   // 245

// ---------------- common kernels ----------------

__global__ void init_cur_kernel(const float* __restrict__ ue,
                                const float* __restrict__ ie,
                                float* __restrict__ cur) {
    long i = (long)blockIdx.x * blockDim.x + threadIdx.x;   // float4 index
    const long n_u4 = (long)N_USERS * EMB / 4;
    const long n_t4 = (long)NTOT * EMB / 4;
    if (i < n_u4) {
        ((float4*)cur)[i] = ((const float4*)ue)[i];
    } else if (i < n_t4) {
        ((float4*)cur)[i] = ((const float4*)ie)[i - n_u4];
    }
}

__global__ void gather_add_kernel(const float* __restrict__ src,
                                  const int* __restrict__ batch,
                                  float* __restrict__ ub,
                                  float* __restrict__ ib) {
    int t    = blockIdx.x * blockDim.x + threadIdx.x;
    int b    = t >> 6;
    int lane = t & 63;
    if (b >= BATCH) return;
    int ur = batch[2 * b];
    int ir = N_USERS + batch[2 * b + 1];
    ub[(long)b * EMB + lane] += src[(long)ur * EMB + lane];
    ib[(long)b * EMB + lane] += src[(long)ir * EMB + lane];
}

__global__ void dot_kernel(const float* __restrict__ ub,
                           const float* __restrict__ ib,
                           float* __restrict__ out) {
    int t    = blockIdx.x * blockDim.x + threadIdx.x;
    int b    = t >> 6;
    int lane = t & 63;
    if (b >= BATCH) return;
    float p = ub[(long)b * EMB + lane] * ib[(long)b * EMB + lane];
    #pragma unroll
    for (int off = 32; off > 0; off >>= 1)
        p += __shfl_down(p, off, 64);
    if (lane == 0) out[b] = p * (1.0f / 16.0f);
}

// ---------------- CSR build ----------------

__global__ void histrank_kernel(const int* __restrict__ rows,
                                int* __restrict__ counts,
                                int* __restrict__ rank) {
    int i = blockIdx.x * blockDim.x + threadIdx.x;
    if (i >= NNZ) return;
    rank[i] = atomicAdd(&counts[rows[i]], 1);
}

__global__ void reduce_counts_kernel(const int* __restrict__ counts, int* __restrict__ bsum) {
    __shared__ int s[256];
    int b = blockIdx.x, t = threadIdx.x;
    int base = b * SCAN_ELEMS + t * 4;
    int sum = 0;
    #pragma unroll
    for (int k = 0; k < 4; ++k) {
        int idx = base + k;
        if (idx < NTOT) sum += counts[idx];
    }
    s[t] = sum;
    __syncthreads();
    for (int off = 128; off > 0; off >>= 1) {
        if (t < off) s[t] += s[t + off];
        __syncthreads();
    }
    if (t == 0) bsum[b] = s[0];
}

__global__ void scan_bsums_kernel(const int* __restrict__ bsum, int* __restrict__ bofs) {
    __shared__ int s[256];
    int t = threadIdx.x;
    s[t] = (t < NBLK_SCAN) ? bsum[t] : 0;
    __syncthreads();
    for (int off = 1; off < 256; off <<= 1) {
        int x = s[t];
        int y = (t >= off) ? s[t - off] : 0;
        __syncthreads();
        s[t] = x + y;
        __syncthreads();
    }
    if (t < NBLK_SCAN) bofs[t] = (t == 0) ? 0 : s[t - 1];
}

__global__ void scan_counts_kernel(const int* __restrict__ counts,
                                   const int* __restrict__ bofs,
                                   int* __restrict__ rowptr) {
    __shared__ int s[256];
    int b = blockIdx.x, t = threadIdx.x;
    int base = b * SCAN_ELEMS + t * 4;
    int c[4];
    int tsum = 0;
    #pragma unroll
    for (int k = 0; k < 4; ++k) {
        int idx = base + k;
        c[k] = (idx < NTOT) ? counts[idx] : 0;
        tsum += c[k];
    }
    s[t] = tsum;
    __syncthreads();
    for (int off = 1; off < 256; off <<= 1) {
        int x = s[t];
        int y = (t >= off) ? s[t - off] : 0;
        __syncthreads();
        s[t] = x + y;
        __syncthreads();
    }
    int excl = (t == 0) ? 0 : s[t - 1];
    int run = bofs[b] + excl;
    #pragma unroll
    for (int k = 0; k < 4; ++k) {
        int idx = base + k;
        if (idx < NTOT) { rowptr[idx] = run; run += c[k]; }
    }
    if (b == 0 && t == 0) rowptr[NTOT] = NNZ;
}

__global__ void scatter_col_kernel(const int* __restrict__ rows,
                                   const int* __restrict__ rank,
                                   const int* __restrict__ cols,
                                   const int* __restrict__ rowptr,
                                   int* __restrict__ pcol) {
    int i = blockIdx.x * blockDim.x + threadIdx.x;
    if (i >= NNZ) return;
    pcol[rowptr[rows[i]] + rank[i]] = cols[i];
}

__global__ void scatter_val_kernel(const int* __restrict__ rows,
                                   const int* __restrict__ rank,
                                   const float* __restrict__ vals,
                                   const int* __restrict__ rowptr,
                                   float* __restrict__ pval) {
    int i = blockIdx.x * blockDim.x + threadIdx.x;
    if (i >= NNZ) return;
    pval[rowptr[rows[i]] + rank[i]] = vals[i];
}

// ---------------- SpMM: 4 rows/wave, 16 lanes/row, float4 gather ----------------
// Per quarter: broadcast-load (col,val) (L1-resident stream), float4 gather,
// dual accumulators for 2-way MLP. Store: one coalesced float4 per lane.

__global__ void spmm_csr_q_kernel(const int* __restrict__ rowptr,
                                  const int* __restrict__ pcol,
                                  const float* __restrict__ pval,
                                  const float4* __restrict__ cur4,
                                  float4* __restrict__ next4) {
    int t    = blockIdx.x * blockDim.x + threadIdx.x;
    int wid  = t >> 6;
    int lane = t & 63;
    int q    = lane >> 4;
    int li   = lane & 15;
    int r    = wid * 4 + q;
    if (r >= NTOT) return;
    int s = rowptr[r];
    int e = rowptr[r + 1];
    float4 a0 = make_float4(0.f, 0.f, 0.f, 0.f);
    float4 a1 = make_float4(0.f, 0.f, 0.f, 0.f);
    int k = s;
    for (; k + 2 <= e; k += 2) {
        int   c0 = pcol[k];
        int   c1 = pcol[k + 1];
        float v0 = pval[k];
        float v1 = pval[k + 1];
        float4 x0 = cur4[c0 * 16 + li];
        float4 x1 = cur4[c1 * 16 + li];
        a0.x += v0 * x0.x; a0.y += v0 * x0.y; a0.z += v0 * x0.z; a0.w += v0 * x0.w;
        a1.x += v1 * x1.x; a1.y += v1 * x1.y; a1.z += v1 * x1.z; a1.w += v1 * x1.w;
    }
    if (k < e) {
        int   c0 = pcol[k];
        float v0 = pval[k];
        float4 x0 = cur4[c0 * 16 + li];
        a0.x += v0 * x0.x; a0.y += v0 * x0.y; a0.z += v0 * x0.z; a0.w += v0 * x0.w;
    }
    float4 o;
    o.x = a0.x + a1.x; o.y = a0.y + a1.y; o.z = a0.z + a1.z; o.w = a0.w + a1.w;
    next4[r * 16 + li] = o;
}

// layer-3 only at batch rows: 4 batch entries/wave, accumulate into ub/ib
__global__ void spmv_batch_kernel(const int* __restrict__ rowptr,
                                  const int* __restrict__ pcol,
                                  const float* __restrict__ pval,
                                  const int* __restrict__ batch,
                                  const float4* __restrict__ cur4,
                                  float4* __restrict__ ub4,
                                  float4* __restrict__ ib4) {
    int t    = blockIdx.x * blockDim.x + threadIdx.x;
    int wid  = t >> 6;
    int lane = t & 63;
    int q    = lane >> 4;
    int li   = lane & 15;
    int idx  = wid * 4 + q;           // 0..2*BATCH-1
    if (idx >= 2 * BATCH) return;
    int b = idx & (BATCH - 1);
    int r;
    float4* dst;
    if (idx < BATCH) { r = batch[2 * b];            dst = ub4; }
    else             { r = N_USERS + batch[2 * b + 1]; dst = ib4; }
    int s = rowptr[r];
    int e = rowptr[r + 1];
    float4 a0 = make_float4(0.f, 0.f, 0.f, 0.f);
    float4 a1 = make_float4(0.f, 0.f, 0.f, 0.f);
    int k = s;
    for (; k + 2 <= e; k += 2) {
        int   c0 = pcol[k];
        int   c1 = pcol[k + 1];
        float v0 = pval[k];
        float v1 = pval[k + 1];
        float4 x0 = cur4[c0 * 16 + li];
        float4 x1 = cur4[c1 * 16 + li];
        a0.x += v0 * x0.x; a0.y += v0 * x0.y; a0.z += v0 * x0.z; a0.w += v0 * x0.w;
        a1.x += v1 * x1.x; a1.y += v1 * x1.y; a1.z += v1 * x1.z; a1.w += v1 * x1.w;
    }
    if (k < e) {
        int   c0 = pcol[k];
        float v0 = pval[k];
        float4 x0 = cur4[c0 * 16 + li];
        a0.x += v0 * x0.x; a0.y += v0 * x0.y; a0.z += v0 * x0.z; a0.w += v0 * x0.w;
    }
    float4 p = dst[b * 16 + li];
    p.x += a0.x + a1.x; p.y += a0.y + a1.y; p.z += a0.z + a1.z; p.w += a0.w + a1.w;
    dst[b * 16 + li] = p;
}

// ---------------- fallback atomic SpMM (small-ws path) ----------------

__global__ void spmm_atomic_kernel(const int* __restrict__ rows,
                                   const int* __restrict__ cols,
                                   const float* __restrict__ vals,
                                   const float* __restrict__ cur,
                                   float* __restrict__ next) {
    int t    = blockIdx.x * blockDim.x + threadIdx.x;
    int nz   = t >> 6;
    int lane = t & 63;
    if (nz >= NNZ) return;
    int   r = rows[nz];
    int   c = cols[nz];
    float v = vals[nz];
    float x = cur[(long)c * EMB + lane];
    atomicAdd(&next[(long)r * EMB + lane], v * x);
}

// ---------------- launch ----------------

extern "C" void kernel_launch(void* const* d_in, const int* in_sizes, int n_in,
                              void* d_out, int out_size, void* d_ws, size_t ws_size,
                              hipStream_t stream) {
    const float* ue    = (const float*)d_in[0];
    const float* ie    = (const float*)d_in[1];
    const int*   rows  = (const int*)d_in[2];
    const int*   cols  = (const int*)d_in[3];
    const float* vals  = (const float*)d_in[4];
    const int*   batch = (const int*)d_in[5];
    float*       out   = (float*)d_out;

    const size_t EMB_BYTES = (size_t)NTOT * EMB * sizeof(float);   // 64,000,000
    const size_t BUF_BYTES = (size_t)BATCH * EMB * sizeof(float);  // 4,194,304
    const size_t NZI_BYTES = (size_t)NNZ * sizeof(int);            // 20,000,000
    const size_t PTR_BYTES = ((size_t)(NTOT + 1) * sizeof(int) + 255) & ~(size_t)255;
    const size_t CNT_BYTES = ((size_t)NTOT * sizeof(int) + 255) & ~(size_t)255;
    const size_t BSM_BYTES = 4096;

    char* ws = (char*)d_ws;
    size_t off = 0;
    float* cur    = (float*)(ws + off); off += EMB_BYTES;
    float* nxt    = (float*)(ws + off); off += EMB_BYTES;
    float* ub     = (float*)(ws + off); off += BUF_BYTES;
    float* ib     = (float*)(ws + off); off += BUF_BYTES;   // ub,ib contiguous
    int*   pcol   = (int*)(ws + off);   off += NZI_BYTES;
    float* pval   = (float*)(ws + off); off += NZI_BYTES;
    int*   rank   = (int*)(ws + off);   off += NZI_BYTES;
    int*   rowptr = (int*)(ws + off);   off += PTR_BYTES;
    int*   counts = (int*)(ws + off);   off += CNT_BYTES;
    int*   bsum   = (int*)(ws + off);   off += BSM_BYTES;
    int*   bofs   = (int*)(ws + off);   off += BSM_BYTES;
    const size_t NEEDED_CSR = off;

    // 1) cur = concat(emb)
    {
        int n_t4 = NTOT * (EMB / 4);
        init_cur_kernel<<<(n_t4 + 255) / 256, 256, 0, stream>>>(ue, ie, cur);
    }
    // 2) layer-0 contribution at batch rows
    hipMemsetAsync(ub, 0, 2 * BUF_BYTES, stream);
    gather_add_kernel<<<(BATCH * 64) / 256, 256, 0, stream>>>(cur, batch, ub, ib);

    if (ws_size >= NEEDED_CSR) {
        // 3) build CSR: hist+rank -> 2-level scan -> two 4B scatter passes
        hipMemsetAsync(counts, 0, CNT_BYTES, stream);
        const int NZB = (NNZ + 255) / 256;
        histrank_kernel<<<NZB, 256, 0, stream>>>(rows, counts, rank);
        reduce_counts_kernel<<<NBLK_SCAN, 256, 0, stream>>>(counts, bsum);
        scan_bsums_kernel<<<1, 256, 0, stream>>>(bsum, bofs);
        scan_counts_kernel<<<NBLK_SCAN, 256, 0, stream>>>(counts, bofs, rowptr);
        scatter_col_kernel<<<NZB, 256, 0, stream>>>(rows, rank, cols, rowptr, pcol);
        scatter_val_kernel<<<NZB, 256, 0, stream>>>(rows, rank, vals, rowptr, pval);

        // 4) layers 1,2 full; layer 3 only at batch rows
        for (int l = 0; l < 2; ++l) {
            spmm_csr_q_kernel<<<(NTOT / 4 * 64) / 256, 256, 0, stream>>>(
                rowptr, pcol, pval, (const float4*)cur, (float4*)nxt);
            gather_add_kernel<<<(BATCH * 64) / 256, 256, 0, stream>>>(nxt, batch, ub, ib);
            float* tmp = cur; cur = nxt; nxt = tmp;
        }
        spmv_batch_kernel<<<(2 * BATCH / 4 * 64) / 256, 256, 0, stream>>>(
            rowptr, pcol, pval, batch, (const float4*)cur, (float4*)ub, (float4*)ib);
    } else {
        // fallback: atomic path (fits in 136.4 MB)
        for (int l = 0; l < 3; ++l) {
            hipMemsetAsync(nxt, 0, EMB_BYTES, stream);
            spmm_atomic_kernel<<<NNZ / 4, 256, 0, stream>>>(rows, cols, vals, cur, nxt);
            gather_add_kernel<<<(BATCH * 64) / 256, 256, 0, stream>>>(nxt, batch, ub, ib);
            float* tmp = cur; cur = nxt; nxt = tmp;
        }
    }

    // 5) score
    dot_kernel<<<(BATCH * 64) / 256, 256, 0, stream>>>(ub, ib, out);
}

// Round 5
// 972.232 us; speedup vs baseline: 3.5506x; 1.0449x over previous
//
#include <hip/hip_runtime.h>

#define N_USERS 200000
#define N_ITEMS 50000
#define NTOT    250000
#define NNZ     5000000
#define EMB     64
#define BATCH   16384

#define SCAN_ELEMS 1024
#define NBLK_SCAN ((NTOT + SCAN_ELEMS - 1) / SCAN_ELEMS)   // 245
#define CSH 4   // counts spread: one counter per 16 ints (64B line)

// ---------------- common kernels ----------------

__global__ void init_cur_kernel(const float* __restrict__ ue,
                                const float* __restrict__ ie,
                                float* __restrict__ cur) {
    long i = (long)blockIdx.x * blockDim.x + threadIdx.x;   // float4 index
    const long n_u4 = (long)N_USERS * EMB / 4;
    const long n_t4 = (long)NTOT * EMB / 4;
    if (i < n_u4) {
        ((float4*)cur)[i] = ((const float4*)ue)[i];
    } else if (i < n_t4) {
        ((float4*)cur)[i] = ((const float4*)ie)[i - n_u4];
    }
}

__global__ void gather_add_kernel(const float* __restrict__ src,
                                  const int* __restrict__ batch,
                                  float* __restrict__ ub,
                                  float* __restrict__ ib) {
    int t    = blockIdx.x * blockDim.x + threadIdx.x;
    int b    = t >> 6;
    int lane = t & 63;
    if (b >= BATCH) return;
    int ur = batch[2 * b];
    int ir = N_USERS + batch[2 * b + 1];
    ub[(long)b * EMB + lane] += src[(long)ur * EMB + lane];
    ib[(long)b * EMB + lane] += src[(long)ir * EMB + lane];
}

__global__ void dot_kernel(const float* __restrict__ ub,
                           const float* __restrict__ ib,
                           float* __restrict__ out) {
    int t    = blockIdx.x * blockDim.x + threadIdx.x;
    int b    = t >> 6;
    int lane = t & 63;
    if (b >= BATCH) return;
    float p = ub[(long)b * EMB + lane] * ib[(long)b * EMB + lane];
    #pragma unroll
    for (int off = 32; off > 0; off >>= 1)
        p += __shfl_down(p, off, 64);
    if (lane == 0) out[b] = p * (1.0f / 16.0f);
}

// ---------------- CSR build ----------------

// histogram (spread counters: 1 per 64B line) + per-nz rank in one pass
__global__ void histrank_kernel(const int* __restrict__ rows,
                                int* __restrict__ counts,
                                int* __restrict__ rank) {
    int i = blockIdx.x * blockDim.x + threadIdx.x;
    if (i >= NNZ) return;
    rank[i] = atomicAdd(&counts[rows[i] << CSH], 1);
}

__global__ void reduce_counts_kernel(const int* __restrict__ counts, int* __restrict__ bsum) {
    __shared__ int s[256];
    int b = blockIdx.x, t = threadIdx.x;
    int base = b * SCAN_ELEMS + t * 4;
    int sum = 0;
    #pragma unroll
    for (int k = 0; k < 4; ++k) {
        int idx = base + k;
        if (idx < NTOT) sum += counts[idx << CSH];
    }
    s[t] = sum;
    __syncthreads();
    for (int off = 128; off > 0; off >>= 1) {
        if (t < off) s[t] += s[t + off];
        __syncthreads();
    }
    if (t == 0) bsum[b] = s[0];
}

__global__ void scan_bsums_kernel(const int* __restrict__ bsum, int* __restrict__ bofs) {
    __shared__ int s[256];
    int t = threadIdx.x;
    s[t] = (t < NBLK_SCAN) ? bsum[t] : 0;
    __syncthreads();
    for (int off = 1; off < 256; off <<= 1) {
        int x = s[t];
        int y = (t >= off) ? s[t - off] : 0;
        __syncthreads();
        s[t] = x + y;
        __syncthreads();
    }
    if (t < NBLK_SCAN) bofs[t] = (t == 0) ? 0 : s[t - 1];
}

__global__ void scan_counts_kernel(const int* __restrict__ counts,
                                   const int* __restrict__ bofs,
                                   int* __restrict__ rowptr) {
    __shared__ int s[256];
    int b = blockIdx.x, t = threadIdx.x;
    int base = b * SCAN_ELEMS + t * 4;
    int c[4];
    int tsum = 0;
    #pragma unroll
    for (int k = 0; k < 4; ++k) {
        int idx = base + k;
        c[k] = (idx < NTOT) ? counts[idx << CSH] : 0;
        tsum += c[k];
    }
    s[t] = tsum;
    __syncthreads();
    for (int off = 1; off < 256; off <<= 1) {
        int x = s[t];
        int y = (t >= off) ? s[t - off] : 0;
        __syncthreads();
        s[t] = x + y;
        __syncthreads();
    }
    int excl = (t == 0) ? 0 : s[t - 1];
    int run = bofs[b] + excl;
    #pragma unroll
    for (int k = 0; k < 4; ++k) {
        int idx = base + k;
        if (idx < NTOT) { rowptr[idx] = run; run += c[k]; }
    }
    if (b == 0 && t == 0) rowptr[NTOT] = NNZ;
}

// pass 1: compute absolute position, cache it into rank[], scatter col
__global__ void scatter_col_kernel(const int* __restrict__ rows,
                                   int* __restrict__ rank,
                                   const int* __restrict__ cols,
                                   const int* __restrict__ rowptr,
                                   int* __restrict__ pcol) {
    int i = blockIdx.x * blockDim.x + threadIdx.x;
    if (i >= NNZ) return;
    int p = rowptr[rows[i]] + rank[i];
    rank[i] = p;
    pcol[p] = cols[i];
}

// pass 2: position already absolute
__global__ void scatter_val_kernel(const int* __restrict__ rank,
                                   const float* __restrict__ vals,
                                   float* __restrict__ pval) {
    int i = blockIdx.x * blockDim.x + threadIdx.x;
    if (i >= NNZ) return;
    pval[rank[i]] = vals[i];
}

// ---------------- SpMM: 4 rows/wave, 16 lanes/row, float4 gather, 4-unroll ----

__global__ void spmm_csr_q_kernel(const int* __restrict__ rowptr,
                                  const int* __restrict__ pcol,
                                  const float* __restrict__ pval,
                                  const float4* __restrict__ cur4,
                                  float4* __restrict__ next4) {
    int t    = blockIdx.x * blockDim.x + threadIdx.x;
    int wid  = t >> 6;
    int lane = t & 63;
    int q    = lane >> 4;
    int li   = lane & 15;
    int r    = wid * 4 + q;
    if (r >= NTOT) return;
    int s = rowptr[r];
    int e = rowptr[r + 1];
    float4 a0 = make_float4(0.f, 0.f, 0.f, 0.f);
    float4 a1 = make_float4(0.f, 0.f, 0.f, 0.f);
    float4 a2 = make_float4(0.f, 0.f, 0.f, 0.f);
    float4 a3 = make_float4(0.f, 0.f, 0.f, 0.f);
    int k = s;
    for (; k + 4 <= e; k += 4) {
        int   c0 = pcol[k];
        int   c1 = pcol[k + 1];
        int   c2 = pcol[k + 2];
        int   c3 = pcol[k + 3];
        float v0 = pval[k];
        float v1 = pval[k + 1];
        float v2 = pval[k + 2];
        float v3 = pval[k + 3];
        float4 x0 = cur4[c0 * 16 + li];
        float4 x1 = cur4[c1 * 16 + li];
        float4 x2 = cur4[c2 * 16 + li];
        float4 x3 = cur4[c3 * 16 + li];
        a0.x += v0 * x0.x; a0.y += v0 * x0.y; a0.z += v0 * x0.z; a0.w += v0 * x0.w;
        a1.x += v1 * x1.x; a1.y += v1 * x1.y; a1.z += v1 * x1.z; a1.w += v1 * x1.w;
        a2.x += v2 * x2.x; a2.y += v2 * x2.y; a2.z += v2 * x2.z; a2.w += v2 * x2.w;
        a3.x += v3 * x3.x; a3.y += v3 * x3.y; a3.z += v3 * x3.z; a3.w += v3 * x3.w;
    }
    for (; k < e; ++k) {
        int   c0 = pcol[k];
        float v0 = pval[k];
        float4 x0 = cur4[c0 * 16 + li];
        a0.x += v0 * x0.x; a0.y += v0 * x0.y; a0.z += v0 * x0.z; a0.w += v0 * x0.w;
    }
    float4 o;
    o.x = (a0.x + a1.x) + (a2.x + a3.x);
    o.y = (a0.y + a1.y) + (a2.y + a3.y);
    o.z = (a0.z + a1.z) + (a2.z + a3.z);
    o.w = (a0.w + a1.w) + (a2.w + a3.w);
    next4[r * 16 + li] = o;
}

// layer-3 only at batch rows: 4 batch entries/wave, accumulate into ub/ib
__global__ void spmv_batch_kernel(const int* __restrict__ rowptr,
                                  const int* __restrict__ pcol,
                                  const float* __restrict__ pval,
                                  const int* __restrict__ batch,
                                  const float4* __restrict__ cur4,
                                  float4* __restrict__ ub4,
                                  float4* __restrict__ ib4) {
    int t    = blockIdx.x * blockDim.x + threadIdx.x;
    int wid  = t >> 6;
    int lane = t & 63;
    int q    = lane >> 4;
    int li   = lane & 15;
    int idx  = wid * 4 + q;           // 0..2*BATCH-1
    if (idx >= 2 * BATCH) return;
    int b = idx & (BATCH - 1);
    int r;
    float4* dst;
    if (idx < BATCH) { r = batch[2 * b];               dst = ub4; }
    else             { r = N_USERS + batch[2 * b + 1]; dst = ib4; }
    int s = rowptr[r];
    int e = rowptr[r + 1];
    float4 a0 = make_float4(0.f, 0.f, 0.f, 0.f);
    float4 a1 = make_float4(0.f, 0.f, 0.f, 0.f);
    float4 a2 = make_float4(0.f, 0.f, 0.f, 0.f);
    float4 a3 = make_float4(0.f, 0.f, 0.f, 0.f);
    int k = s;
    for (; k + 4 <= e; k += 4) {
        int   c0 = pcol[k];
        int   c1 = pcol[k + 1];
        int   c2 = pcol[k + 2];
        int   c3 = pcol[k + 3];
        float v0 = pval[k];
        float v1 = pval[k + 1];
        float v2 = pval[k + 2];
        float v3 = pval[k + 3];
        float4 x0 = cur4[c0 * 16 + li];
        float4 x1 = cur4[c1 * 16 + li];
        float4 x2 = cur4[c2 * 16 + li];
        float4 x3 = cur4[c3 * 16 + li];
        a0.x += v0 * x0.x; a0.y += v0 * x0.y; a0.z += v0 * x0.z; a0.w += v0 * x0.w;
        a1.x += v1 * x1.x; a1.y += v1 * x1.y; a1.z += v1 * x1.z; a1.w += v1 * x1.w;
        a2.x += v2 * x2.x; a2.y += v2 * x2.y; a2.z += v2 * x2.z; a2.w += v2 * x2.w;
        a3.x += v3 * x3.x; a3.y += v3 * x3.y; a3.z += v3 * x3.z; a3.w += v3 * x3.w;
    }
    for (; k < e; ++k) {
        int   c0 = pcol[k];
        float v0 = pval[k];
        float4 x0 = cur4[c0 * 16 + li];
        a0.x += v0 * x0.x; a0.y += v0 * x0.y; a0.z += v0 * x0.z; a0.w += v0 * x0.w;
    }
    float4 p = dst[b * 16 + li];
    p.x += (a0.x + a1.x) + (a2.x + a3.x);
    p.y += (a0.y + a1.y) + (a2.y + a3.y);
    p.z += (a0.z + a1.z) + (a2.z + a3.z);
    p.w += (a0.w + a1.w) + (a2.w + a3.w);
    dst[b * 16 + li] = p;
}

// ---------------- fallback atomic SpMM (small-ws path) ----------------

__global__ void spmm_atomic_kernel(const int* __restrict__ rows,
                                   const int* __restrict__ cols,
                                   const float* __restrict__ vals,
                                   const float* __restrict__ cur,
                                   float* __restrict__ next) {
    int t    = blockIdx.x * blockDim.x + threadIdx.x;
    int nz   = t >> 6;
    int lane = t & 63;
    if (nz >= NNZ) return;
    int   r = rows[nz];
    int   c = cols[nz];
    float v = vals[nz];
    float x = cur[(long)c * EMB + lane];
    atomicAdd(&next[(long)r * EMB + lane], v * x);
}

// ---------------- launch ----------------

extern "C" void kernel_launch(void* const* d_in, const int* in_sizes, int n_in,
                              void* d_out, int out_size, void* d_ws, size_t ws_size,
                              hipStream_t stream) {
    const float* ue    = (const float*)d_in[0];
    const float* ie    = (const float*)d_in[1];
    const int*   rows  = (const int*)d_in[2];
    const int*   cols  = (const int*)d_in[3];
    const float* vals  = (const float*)d_in[4];
    const int*   batch = (const int*)d_in[5];
    float*       out   = (float*)d_out;

    const size_t EMB_BYTES  = (size_t)NTOT * EMB * sizeof(float);       // 64,000,000
    const size_t BUF_BYTES  = (size_t)BATCH * EMB * sizeof(float);      // 4,194,304
    const size_t NZI_BYTES  = (size_t)NNZ * sizeof(int);                // 20,000,000
    const size_t PTR_BYTES  = ((size_t)(NTOT + 1) * sizeof(int) + 255) & ~(size_t)255;
    const size_t CNTS_BYTES = ((size_t)NTOT << CSH) * sizeof(int);      // 16,000,000 (spread)

    char* ws = (char*)d_ws;
    size_t off = 0;
    float* cur    = (float*)(ws + off); off += EMB_BYTES;
    float* nxt    = (float*)(ws + off); off += EMB_BYTES;
    float* ub     = (float*)(ws + off); off += BUF_BYTES;
    float* ib     = (float*)(ws + off); off += BUF_BYTES;   // ub,ib contiguous
    int*   pcol   = (int*)(ws + off);   off += NZI_BYTES;
    float* pval   = (float*)(ws + off); off += NZI_BYTES;
    int*   rowptr = (int*)(ws + off);   off += PTR_BYTES;
    const size_t NEEDED_CSR = off;

    // Build-time scratch ALIASED into nxt (all dead before first spmm writes nxt):
    //   rank   @ nxt+0        (20 MB)
    //   counts @ nxt+20MB     (16 MB, spread 1 counter / 64B)
    //   bsum   @ nxt+36MB, bofs @ nxt+36MB+4KB
    int* rank   = (int*)((char*)nxt);
    int* counts = (int*)((char*)nxt + NZI_BYTES);
    int* bsum   = (int*)((char*)nxt + NZI_BYTES + CNTS_BYTES);
    int* bofs   = (int*)((char*)nxt + NZI_BYTES + CNTS_BYTES + 4096);

    // 1) cur = concat(emb)
    {
        int n_t4 = NTOT * (EMB / 4);
        init_cur_kernel<<<(n_t4 + 255) / 256, 256, 0, stream>>>(ue, ie, cur);
    }
    // 2) layer-0 contribution at batch rows
    hipMemsetAsync(ub, 0, 2 * BUF_BYTES, stream);
    gather_add_kernel<<<(BATCH * 64) / 256, 256, 0, stream>>>(cur, batch, ub, ib);

    if (ws_size >= NEEDED_CSR) {
        // 3) build CSR: hist+rank (spread counters) -> 2-level scan -> 2 scatters
        hipMemsetAsync(counts, 0, CNTS_BYTES, stream);
        const int NZB = (NNZ + 255) / 256;
        histrank_kernel<<<NZB, 256, 0, stream>>>(rows, counts, rank);
        reduce_counts_kernel<<<NBLK_SCAN, 256, 0, stream>>>(counts, bsum);
        scan_bsums_kernel<<<1, 256, 0, stream>>>(bsum, bofs);
        scan_counts_kernel<<<NBLK_SCAN, 256, 0, stream>>>(counts, bofs, rowptr);
        scatter_col_kernel<<<NZB, 256, 0, stream>>>(rows, rank, cols, rowptr, pcol);
        scatter_val_kernel<<<NZB, 256, 0, stream>>>(rank, vals, pval);

        // 4) layers 1,2 full; layer 3 only at batch rows
        for (int l = 0; l < 2; ++l) {
            spmm_csr_q_kernel<<<(NTOT / 4 * 64) / 256, 256, 0, stream>>>(
                rowptr, pcol, pval, (const float4*)cur, (float4*)nxt);
            gather_add_kernel<<<(BATCH * 64) / 256, 256, 0, stream>>>(nxt, batch, ub, ib);
            float* tmp = cur; cur = nxt; nxt = tmp;
        }
        spmv_batch_kernel<<<(2 * BATCH / 4 * 64) / 256, 256, 0, stream>>>(
            rowptr, pcol, pval, batch, (const float4*)cur, (float4*)ub, (float4*)ib);
    } else {
        // fallback: atomic path (fits in 136.4 MB)
        for (int l = 0; l < 3; ++l) {
            hipMemsetAsync(nxt, 0, EMB_BYTES, stream);
            spmm_atomic_kernel<<<NNZ / 4, 256, 0, stream>>>(rows, cols, vals, cur, nxt);
            gather_add_kernel<<<(BATCH * 64) / 256, 256, 0, stream>>>(nxt, batch, ub, ib);
            float* tmp = cur; cur = nxt; nxt = tmp;
        }
    }

    // 5) score
    dot_kernel<<<(BATCH * 64) / 256, 256, 0, stream>>>(ub, ib, out);
}

// Round 6
// 864.030 us; speedup vs baseline: 3.9953x; 1.1252x over previous
//
#include <hip/hip_runtime.h>

#define N_USERS 200000
#define N_ITEMS 50000
#define NTOT    250000
#define NNZ     5000000
#define EMB     64
#define BATCH   16384

// ---- bucket-build parameters ----
#define EPB     4096                         // elements per partition block
#define NBLK_P  ((NNZ + EPB - 1) / EPB)      // 1221
#define NBUCK   ((NTOT + 127) >> 7)          // 1954 buckets of 128 rows
#define BPAD    2048                         // padded bucket count (LDS/row stride)
#define MAXB    3072                         // max bucket size (mean 2560, +10 sigma)

// ---------------- common kernels ----------------

__global__ void init_cur_kernel(const float* __restrict__ ue,
                                const float* __restrict__ ie,
                                float* __restrict__ cur) {
    long i = (long)blockIdx.x * blockDim.x + threadIdx.x;   // float4 index
    const long n_u4 = (long)N_USERS * EMB / 4;
    const long n_t4 = (long)NTOT * EMB / 4;
    if (i < n_u4) {
        ((float4*)cur)[i] = ((const float4*)ue)[i];
    } else if (i < n_t4) {
        ((float4*)cur)[i] = ((const float4*)ie)[i - n_u4];
    }
}

__global__ void gather_add_kernel(const float* __restrict__ src,
                                  const int* __restrict__ batch,
                                  float* __restrict__ ub,
                                  float* __restrict__ ib) {
    int t    = blockIdx.x * blockDim.x + threadIdx.x;
    int b    = t >> 6;
    int lane = t & 63;
    if (b >= BATCH) return;
    int ur = batch[2 * b];
    int ir = N_USERS + batch[2 * b + 1];
    ub[(long)b * EMB + lane] += src[(long)ur * EMB + lane];
    ib[(long)b * EMB + lane] += src[(long)ir * EMB + lane];
}

__global__ void dot_kernel(const float* __restrict__ ub,
                           const float* __restrict__ ib,
                           float* __restrict__ out) {
    int t    = blockIdx.x * blockDim.x + threadIdx.x;
    int b    = t >> 6;
    int lane = t & 63;
    if (b >= BATCH) return;
    float p = ub[(long)b * EMB + lane] * ib[(long)b * EMB + lane];
    #pragma unroll
    for (int off = 32; off > 0; off >>= 1)
        p += __shfl_down(p, off, 64);
    if (lane == 0) out[b] = p * (1.0f / 16.0f);
}

// ---------------- atomic-free CSR build ----------------

// k1: per-block LDS histogram over buckets; coalesced write of H row.
__global__ void part_hist_kernel(const int* __restrict__ rows, int* __restrict__ H) {
    __shared__ int h[BPAD];
    int b = blockIdx.x, t = threadIdx.x;
    for (int k = t; k < BPAD; k += 256) h[k] = 0;
    __syncthreads();
    int s = b * EPB;
    int e = s + EPB; if (e > NNZ) e = NNZ;
    for (int i = s + t; i < e; i += 256)
        atomicAdd(&h[rows[i] >> 7], 1);
    __syncthreads();
    for (int k = t; k < BPAD; k += 256) H[b * BPAD + k] = h[k];
}

// k2a: exclusive scan of each H column (over blocks), in place; ctot[k] = column sum.
__global__ void col_scan_kernel(int* __restrict__ H, int* __restrict__ ctot) {
    __shared__ int s[256];
    int k = blockIdx.x;       // bucket
    int t = threadIdx.x;
    int v[5]; int tsum = 0;
    #pragma unroll
    for (int j = 0; j < 5; ++j) {
        int b = t * 5 + j;
        v[j] = (b < NBLK_P) ? H[b * BPAD + k] : 0;
        tsum += v[j];
    }
    s[t] = tsum;
    __syncthreads();
    for (int off = 1; off < 256; off <<= 1) {
        int x = s[t];
        int y = (t >= off) ? s[t - off] : 0;
        __syncthreads();
        s[t] = x + y;
        __syncthreads();
    }
    int run = (t == 0) ? 0 : s[t - 1];
    #pragma unroll
    for (int j = 0; j < 5; ++j) {
        int b = t * 5 + j;
        if (b < NBLK_P) { H[b * BPAD + k] = run; run += v[j]; }
    }
    if (t == 255) ctot[k] = s[255];
}

// k2b: exclusive scan over bucket totals -> cbase[0..NBUCK], rowptr[NTOT]=NNZ.
__global__ void bucket_scan_kernel(const int* __restrict__ ctot,
                                   int* __restrict__ cbase,
                                   int* __restrict__ rowptr) {
    __shared__ int s[256];
    int t = threadIdx.x;
    int v[8]; int tsum = 0;
    #pragma unroll
    for (int j = 0; j < 8; ++j) {
        int k = t * 8 + j;
        v[j] = (k < NBUCK) ? ctot[k] : 0;
        tsum += v[j];
    }
    s[t] = tsum;
    __syncthreads();
    for (int off = 1; off < 256; off <<= 1) {
        int x = s[t];
        int y = (t >= off) ? s[t - off] : 0;
        __syncthreads();
        s[t] = x + y;
        __syncthreads();
    }
    int run = (t == 0) ? 0 : s[t - 1];
    #pragma unroll
    for (int j = 0; j < 8; ++j) {
        int k = t * 8 + j;
        if (k < NBUCK)       { cbase[k] = run; run += v[j]; }
        else if (k == NBUCK) { cbase[k] = run; }              // == NNZ
    }
    if (t == 0) rowptr[NTOT] = NNZ;
}

// k3: partition scatter. slot = cbase[k] + H[b][k] + LDS-rank. No global atomics.
// payload: pk = col | (row&127)<<18 ; pv = val  (SoA: 20MB dirty footprint each)
__global__ void part_scatter_kernel(const int* __restrict__ rows,
                                    const int* __restrict__ cols,
                                    const float* __restrict__ vals,
                                    const int* __restrict__ H,
                                    const int* __restrict__ cbase,
                                    int* __restrict__ pk,
                                    float* __restrict__ pv) {
    __shared__ int bb[BPAD];
    __shared__ int h2[BPAD];
    int b = blockIdx.x, t = threadIdx.x;
    for (int k = t; k < BPAD; k += 256) {
        bb[k] = (k < NBUCK) ? (cbase[k] + H[b * BPAD + k]) : 0;
        h2[k] = 0;
    }
    __syncthreads();
    int s = b * EPB;
    int e = s + EPB; if (e > NNZ) e = NNZ;
    for (int i = s + t; i < e; i += 256) {
        int r = rows[i];
        int k = r >> 7;
        int rank = atomicAdd(&h2[k], 1);     // LDS atomic
        int pos  = bb[k] + rank;
        pk[pos] = cols[i] | ((r & 127) << 18);
        pv[pos] = vals[i];
    }
}

// k4: one block per bucket: LDS counting sort over 128 rows -> rowptr + final pcol/pval.
__global__ void bucket_sort_kernel(const int* __restrict__ cbase,
                                   const int* __restrict__ pk,
                                   const float* __restrict__ pv,
                                   int* __restrict__ rowptr,
                                   int* __restrict__ pcol,
                                   float* __restrict__ pval) {
    __shared__ int   eL[MAXB];
    __shared__ float vL[MAXB];
    __shared__ int   cnt[128], sc[128], ofs[128];
    int k = blockIdx.x, t = threadIdx.x;
    int s = cbase[k];
    int e = cbase[k + 1];
    int n = e - s;
    if (t < 128) cnt[t] = 0;
    __syncthreads();
    for (int i = t; i < n; i += 256) {
        int   w = pk[s + i];
        float f = pv[s + i];
        if (i < MAXB) { eL[i] = w; vL[i] = f; }
        atomicAdd(&cnt[(w >> 18) & 127], 1);
    }
    __syncthreads();
    if (t < 128) sc[t] = cnt[t];
    __syncthreads();
    for (int off = 1; off < 128; off <<= 1) {
        int x = 0;
        if (t < 128) { x = sc[t]; if (t >= off) x += sc[t - off]; }
        __syncthreads();
        if (t < 128) sc[t] = x;
        __syncthreads();
    }
    if (t < 128) {
        int rs = sc[t] - cnt[t];             // exclusive start for row t
        ofs[t] = rs;
        int r = (k << 7) + t;
        if (r < NTOT) rowptr[r] = s + rs;
    }
    __syncthreads();
    for (int i = t; i < n; i += 256) {
        int w; float f;
        if (i < MAXB) { w = eL[i]; f = vL[i]; }
        else          { w = pk[s + i]; f = pv[s + i]; }   // overflow safety
        int r7 = (w >> 18) & 127;
        int p  = atomicAdd(&ofs[r7], 1);     // LDS atomic
        pcol[s + p] = w & 0x3FFFF;
        pval[s + p] = f;
    }
}

// ---------------- SpMM: 4 rows/wave, 16 lanes/row, float4 gather, 4-unroll ----

__global__ void spmm_csr_q_kernel(const int* __restrict__ rowptr,
                                  const int* __restrict__ pcol,
                                  const float* __restrict__ pval,
                                  const float4* __restrict__ cur4,
                                  float4* __restrict__ next4) {
    int t    = blockIdx.x * blockDim.x + threadIdx.x;
    int wid  = t >> 6;
    int lane = t & 63;
    int q    = lane >> 4;
    int li   = lane & 15;
    int r    = wid * 4 + q;
    if (r >= NTOT) return;
    int s = rowptr[r];
    int e = rowptr[r + 1];
    float4 a0 = make_float4(0.f, 0.f, 0.f, 0.f);
    float4 a1 = make_float4(0.f, 0.f, 0.f, 0.f);
    float4 a2 = make_float4(0.f, 0.f, 0.f, 0.f);
    float4 a3 = make_float4(0.f, 0.f, 0.f, 0.f);
    int k = s;
    for (; k + 4 <= e; k += 4) {
        int   c0 = pcol[k];
        int   c1 = pcol[k + 1];
        int   c2 = pcol[k + 2];
        int   c3 = pcol[k + 3];
        float v0 = pval[k];
        float v1 = pval[k + 1];
        float v2 = pval[k + 2];
        float v3 = pval[k + 3];
        float4 x0 = cur4[c0 * 16 + li];
        float4 x1 = cur4[c1 * 16 + li];
        float4 x2 = cur4[c2 * 16 + li];
        float4 x3 = cur4[c3 * 16 + li];
        a0.x += v0 * x0.x; a0.y += v0 * x0.y; a0.z += v0 * x0.z; a0.w += v0 * x0.w;
        a1.x += v1 * x1.x; a1.y += v1 * x1.y; a1.z += v1 * x1.z; a1.w += v1 * x1.w;
        a2.x += v2 * x2.x; a2.y += v2 * x2.y; a2.z += v2 * x2.z; a2.w += v2 * x2.w;
        a3.x += v3 * x3.x; a3.y += v3 * x3.y; a3.z += v3 * x3.z; a3.w += v3 * x3.w;
    }
    for (; k < e; ++k) {
        int   c0 = pcol[k];
        float v0 = pval[k];
        float4 x0 = cur4[c0 * 16 + li];
        a0.x += v0 * x0.x; a0.y += v0 * x0.y; a0.z += v0 * x0.z; a0.w += v0 * x0.w;
    }
    float4 o;
    o.x = (a0.x + a1.x) + (a2.x + a3.x);
    o.y = (a0.y + a1.y) + (a2.y + a3.y);
    o.z = (a0.z + a1.z) + (a2.z + a3.z);
    o.w = (a0.w + a1.w) + (a2.w + a3.w);
    next4[r * 16 + li] = o;
}

// layer-3 only at batch rows: 4 batch entries/wave, accumulate into ub/ib
__global__ void spmv_batch_kernel(const int* __restrict__ rowptr,
                                  const int* __restrict__ pcol,
                                  const float* __restrict__ pval,
                                  const int* __restrict__ batch,
                                  const float4* __restrict__ cur4,
                                  float4* __restrict__ ub4,
                                  float4* __restrict__ ib4) {
    int t    = blockIdx.x * blockDim.x + threadIdx.x;
    int wid  = t >> 6;
    int lane = t & 63;
    int q    = lane >> 4;
    int li   = lane & 15;
    int idx  = wid * 4 + q;           // 0..2*BATCH-1
    if (idx >= 2 * BATCH) return;
    int b = idx & (BATCH - 1);
    int r;
    float4* dst;
    if (idx < BATCH) { r = batch[2 * b];               dst = ub4; }
    else             { r = N_USERS + batch[2 * b + 1]; dst = ib4; }
    int s = rowptr[r];
    int e = rowptr[r + 1];
    float4 a0 = make_float4(0.f, 0.f, 0.f, 0.f);
    float4 a1 = make_float4(0.f, 0.f, 0.f, 0.f);
    float4 a2 = make_float4(0.f, 0.f, 0.f, 0.f);
    float4 a3 = make_float4(0.f, 0.f, 0.f, 0.f);
    int k = s;
    for (; k + 4 <= e; k += 4) {
        int   c0 = pcol[k];
        int   c1 = pcol[k + 1];
        int   c2 = pcol[k + 2];
        int   c3 = pcol[k + 3];
        float v0 = pval[k];
        float v1 = pval[k + 1];
        float v2 = pval[k + 2];
        float v3 = pval[k + 3];
        float4 x0 = cur4[c0 * 16 + li];
        float4 x1 = cur4[c1 * 16 + li];
        float4 x2 = cur4[c2 * 16 + li];
        float4 x3 = cur4[c3 * 16 + li];
        a0.x += v0 * x0.x; a0.y += v0 * x0.y; a0.z += v0 * x0.z; a0.w += v0 * x0.w;
        a1.x += v1 * x1.x; a1.y += v1 * x1.y; a1.z += v1 * x1.z; a1.w += v1 * x1.w;
        a2.x += v2 * x2.x; a2.y += v2 * x2.y; a2.z += v2 * x2.z; a2.w += v2 * x2.w;
        a3.x += v3 * x3.x; a3.y += v3 * x3.y; a3.z += v3 * x3.z; a3.w += v3 * x3.w;
    }
    for (; k < e; ++k) {
        int   c0 = pcol[k];
        float v0 = pval[k];
        float4 x0 = cur4[c0 * 16 + li];
        a0.x += v0 * x0.x; a0.y += v0 * x0.y; a0.z += v0 * x0.z; a0.w += v0 * x0.w;
    }
    float4 p = dst[b * 16 + li];
    p.x += (a0.x + a1.x) + (a2.x + a3.x);
    p.y += (a0.y + a1.y) + (a2.y + a3.y);
    p.z += (a0.z + a1.z) + (a2.z + a3.z);
    p.w += (a0.w + a1.w) + (a2.w + a3.w);
    dst[b * 16 + li] = p;
}

// ---------------- fallback atomic SpMM (small-ws path) ----------------

__global__ void spmm_atomic_kernel(const int* __restrict__ rows,
                                   const int* __restrict__ cols,
                                   const float* __restrict__ vals,
                                   const float* __restrict__ cur,
                                   float* __restrict__ next) {
    int t    = blockIdx.x * blockDim.x + threadIdx.x;
    int nz   = t >> 6;
    int lane = t & 63;
    if (nz >= NNZ) return;
    int   r = rows[nz];
    int   c = cols[nz];
    float v = vals[nz];
    float x = cur[(long)c * EMB + lane];
    atomicAdd(&next[(long)r * EMB + lane], v * x);
}

// ---------------- launch ----------------

extern "C" void kernel_launch(void* const* d_in, const int* in_sizes, int n_in,
                              void* d_out, int out_size, void* d_ws, size_t ws_size,
                              hipStream_t stream) {
    const float* ue    = (const float*)d_in[0];
    const float* ie    = (const float*)d_in[1];
    const int*   rows  = (const int*)d_in[2];
    const int*   cols  = (const int*)d_in[3];
    const float* vals  = (const float*)d_in[4];
    const int*   batch = (const int*)d_in[5];
    float*       out   = (float*)d_out;

    const size_t EMB_BYTES = (size_t)NTOT * EMB * sizeof(float);   // 64,000,000
    const size_t BUF_BYTES = (size_t)BATCH * EMB * sizeof(float);  // 4,194,304
    const size_t NZI_BYTES = (size_t)NNZ * sizeof(int);            // 20,000,000
    const size_t PTR_BYTES = ((size_t)(NTOT + 1) * sizeof(int) + 255) & ~(size_t)255;

    char* ws = (char*)d_ws;
    size_t off = 0;
    float* cur    = (float*)(ws + off); off += EMB_BYTES;
    float* nxt    = (float*)(ws + off); off += EMB_BYTES;
    float* ub     = (float*)(ws + off); off += BUF_BYTES;
    float* ib     = (float*)(ws + off); off += BUF_BYTES;   // ub,ib contiguous
    int*   pcol   = (int*)(ws + off);   off += NZI_BYTES;
    float* pval   = (float*)(ws + off); off += NZI_BYTES;
    int*   rowptr = (int*)(ws + off);   off += PTR_BYTES;
    const size_t NEEDED_CSR = off;

    // Build-time scratch ALIASED into nxt (dead before first spmm writes nxt):
    //   pk    @ 0      (20 MB)  partitioned packed col|rowlow
    //   pv    @ 20 MB  (20 MB)  partitioned val
    //   H     @ 40 MB  (NBLK_P * BPAD * 4 = 10.0 MB)
    //   ctot  @ 51 MB  (7.8 KB) ; cbase @ 51 MB + 16 KB (7.8 KB)
    int*   pk    = (int*)((char*)nxt);
    float* pv    = (float*)((char*)nxt + NZI_BYTES);
    int*   H     = (int*)((char*)nxt + 2 * NZI_BYTES);
    int*   ctot  = (int*)((char*)nxt + 2 * NZI_BYTES + (size_t)NBLK_P * BPAD * 4 + 4096);
    int*   cbase = (int*)((char*)nxt + 2 * NZI_BYTES + (size_t)NBLK_P * BPAD * 4 + 20480);

    // 1) cur = concat(emb)
    {
        int n_t4 = NTOT * (EMB / 4);
        init_cur_kernel<<<(n_t4 + 255) / 256, 256, 0, stream>>>(ue, ie, cur);
    }
    // 2) layer-0 contribution at batch rows
    hipMemsetAsync(ub, 0, 2 * BUF_BYTES, stream);
    gather_add_kernel<<<(BATCH * 64) / 256, 256, 0, stream>>>(cur, batch, ub, ib);

    if (ws_size >= NEEDED_CSR) {
        // 3) atomic-free CSR build: bucket hist -> column scan -> partition -> bucket sort
        part_hist_kernel<<<NBLK_P, 256, 0, stream>>>(rows, H);
        col_scan_kernel<<<NBUCK, 256, 0, stream>>>(H, ctot);
        bucket_scan_kernel<<<1, 256, 0, stream>>>(ctot, cbase, rowptr);
        part_scatter_kernel<<<NBLK_P, 256, 0, stream>>>(rows, cols, vals, H, cbase, pk, pv);
        bucket_sort_kernel<<<NBUCK, 256, 0, stream>>>(cbase, pk, pv, rowptr, pcol, pval);

        // 4) layers 1,2 full; layer 3 only at batch rows
        for (int l = 0; l < 2; ++l) {
            spmm_csr_q_kernel<<<(NTOT / 4 * 64) / 256, 256, 0, stream>>>(
                rowptr, pcol, pval, (const float4*)cur, (float4*)nxt);
            gather_add_kernel<<<(BATCH * 64) / 256, 256, 0, stream>>>(nxt, batch, ub, ib);
            float* tmp = cur; cur = nxt; nxt = tmp;
        }
        spmv_batch_kernel<<<(2 * BATCH / 4 * 64) / 256, 256, 0, stream>>>(
            rowptr, pcol, pval, batch, (const float4*)cur, (float4*)ub, (float4*)ib);
    } else {
        // fallback: atomic path (fits in 136.4 MB)
        for (int l = 0; l < 3; ++l) {
            hipMemsetAsync(nxt, 0, EMB_BYTES, stream);
            spmm_atomic_kernel<<<NNZ / 4, 256, 0, stream>>>(rows, cols, vals, cur, nxt);
            gather_add_kernel<<<(BATCH * 64) / 256, 256, 0, stream>>>(nxt, batch, ub, ib);
            float* tmp = cur; cur = nxt; nxt = tmp;
        }
    }

    // 5) score
    dot_kernel<<<(BATCH * 64) / 256, 256, 0, stream>>>(ub, ib, out);
}

// Round 7
// 845.459 us; speedup vs baseline: 4.0830x; 1.0220x over previous
//
#include <hip/hip_runtime.h>

#define N_USERS 200000
#define N_ITEMS 50000
#define NTOT    250000
#define NNZ     5000000
#define EMB     64
#define BATCH   16384

// ---- bucket-build parameters ----
#define EPB     4096                         // elements per partition block
#define NBLK_P  ((NNZ + EPB - 1) / EPB)      // 1221
#define NBUCK   ((NTOT + 127) >> 7)          // 1954 buckets of 128 rows
#define HBUCK   977                          // bucket-range split point
#define BPAD    2048                         // padded bucket stride in H
#define MAXB    3072                         // max bucket size (mean 2560)

// ---------------- common kernels ----------------

__global__ void init_cur_kernel(const float* __restrict__ ue,
                                const float* __restrict__ ie,
                                float* __restrict__ cur) {
    long i = (long)blockIdx.x * blockDim.x + threadIdx.x;   // float4 index
    const long n_u4 = (long)N_USERS * EMB / 4;
    const long n_t4 = (long)NTOT * EMB / 4;
    if (i < n_u4) {
        ((float4*)cur)[i] = ((const float4*)ue)[i];
    } else if (i < n_t4) {
        ((float4*)cur)[i] = ((const float4*)ie)[i - n_u4];
    }
}

__global__ void gather_add_kernel(const float* __restrict__ src,
                                  const int* __restrict__ batch,
                                  float* __restrict__ ub,
                                  float* __restrict__ ib) {
    int t    = blockIdx.x * blockDim.x + threadIdx.x;
    int b    = t >> 6;
    int lane = t & 63;
    if (b >= BATCH) return;
    int ur = batch[2 * b];
    int ir = N_USERS + batch[2 * b + 1];
    ub[(long)b * EMB + lane] += src[(long)ur * EMB + lane];
    ib[(long)b * EMB + lane] += src[(long)ir * EMB + lane];
}

__global__ void dot_kernel(const float* __restrict__ ub,
                           const float* __restrict__ ib,
                           float* __restrict__ out) {
    int t    = blockIdx.x * blockDim.x + threadIdx.x;
    int b    = t >> 6;
    int lane = t & 63;
    if (b >= BATCH) return;
    float p = ub[(long)b * EMB + lane] * ib[(long)b * EMB + lane];
    #pragma unroll
    for (int off = 32; off > 0; off >>= 1)
        p += __shfl_down(p, off, 64);
    if (lane == 0) out[b] = p * (1.0f / 16.0f);
}

// ---------------- atomic-free CSR build ----------------

// k1: per-block LDS histogram over buckets; coalesced write of H row.
__global__ void part_hist_kernel(const int* __restrict__ rows, int* __restrict__ H) {
    __shared__ int h[BPAD];
    int b = blockIdx.x, t = threadIdx.x;
    for (int k = t; k < BPAD; k += 256) h[k] = 0;
    __syncthreads();
    int s = b * EPB;
    int e = s + EPB; if (e > NNZ) e = NNZ;
    for (int i = s + t; i < e; i += 256)
        atomicAdd(&h[rows[i] >> 7], 1);
    __syncthreads();
    for (int k = t; k < BPAD; k += 256) H[b * BPAD + k] = h[k];
}

// k2a: exclusive scan of each H column (over blocks), in place; ctot[k] = column sum.
__global__ void col_scan_kernel(int* __restrict__ H, int* __restrict__ ctot) {
    __shared__ int s[256];
    int k = blockIdx.x;       // bucket
    int t = threadIdx.x;
    int v[5]; int tsum = 0;
    #pragma unroll
    for (int j = 0; j < 5; ++j) {
        int b = t * 5 + j;
        v[j] = (b < NBLK_P) ? H[b * BPAD + k] : 0;
        tsum += v[j];
    }
    s[t] = tsum;
    __syncthreads();
    for (int off = 1; off < 256; off <<= 1) {
        int x = s[t];
        int y = (t >= off) ? s[t - off] : 0;
        __syncthreads();
        s[t] = x + y;
        __syncthreads();
    }
    int run = (t == 0) ? 0 : s[t - 1];
    #pragma unroll
    for (int j = 0; j < 5; ++j) {
        int b = t * 5 + j;
        if (b < NBLK_P) { H[b * BPAD + k] = run; run += v[j]; }
    }
    if (t == 255) ctot[k] = s[255];
}

// k2b: exclusive scan over bucket totals -> cbase[0..NBUCK], rowptr[NTOT]=NNZ.
__global__ void bucket_scan_kernel(const int* __restrict__ ctot,
                                   int* __restrict__ cbase,
                                   int* __restrict__ rowptr) {
    __shared__ int s[256];
    int t = threadIdx.x;
    int v[8]; int tsum = 0;
    #pragma unroll
    for (int j = 0; j < 8; ++j) {
        int k = t * 8 + j;
        v[j] = (k < NBUCK) ? ctot[k] : 0;
        tsum += v[j];
    }
    s[t] = tsum;
    __syncthreads();
    for (int off = 1; off < 256; off <<= 1) {
        int x = s[t];
        int y = (t >= off) ? s[t - off] : 0;
        __syncthreads();
        s[t] = x + y;
        __syncthreads();
    }
    int run = (t == 0) ? 0 : s[t - 1];
    #pragma unroll
    for (int j = 0; j < 8; ++j) {
        int k = t * 8 + j;
        if (k < NBUCK)       { cbase[k] = run; run += v[j]; }
        else if (k == NBUCK) { cbase[k] = run; }              // == NNZ
    }
    if (t == 0) rowptr[NTOT] = NNZ;
}

// k3: partition scatter, BUCKET-RANGE pass [klo,khi). Per-pass random-dirty
// footprint = (khi-klo)/NBUCK * 40 MB -> with a half split: 20 MB < per-XCD L2
// stripe budget, so L2 assembles full lines (the R6 single-pass version wrote
// 308 MB for 40 MB of payload). A bucket is fully handled in one pass, so the
// LDS rank is complete for its (block,bucket).
__global__ void part_scatter_kernel(const int* __restrict__ rows,
                                    const int* __restrict__ cols,
                                    const float* __restrict__ vals,
                                    const int* __restrict__ H,
                                    const int* __restrict__ cbase,
                                    int klo, int khi,
                                    int* __restrict__ pk,
                                    float* __restrict__ pv) {
    __shared__ int bb[1024];
    __shared__ int h2[1024];
    int b = blockIdx.x, t = threadIdx.x;
    int w = khi - klo;                       // <= 1024
    for (int k = t; k < 1024; k += 256) {
        int kk = klo + k;
        bb[k] = (k < w) ? (cbase[kk] + H[b * BPAD + kk]) : 0;
        h2[k] = 0;
    }
    __syncthreads();
    int s = b * EPB;
    int e = s + EPB; if (e > NNZ) e = NNZ;
    for (int i = s + t; i < e; i += 256) {
        int r = rows[i];
        int k = (r >> 7) - klo;
        if ((unsigned)k >= (unsigned)w) continue;
        int rank = atomicAdd(&h2[k], 1);     // LDS atomic
        int pos  = bb[k] + rank;
        pk[pos] = cols[i] | ((r & 127) << 18);
        pv[pos] = vals[i];
    }
}

// k4: one block per bucket: LDS counting sort over 128 rows -> rowptr + final pcol/pval.
__global__ void bucket_sort_kernel(const int* __restrict__ cbase,
                                   const int* __restrict__ pk,
                                   const float* __restrict__ pv,
                                   int* __restrict__ rowptr,
                                   int* __restrict__ pcol,
                                   float* __restrict__ pval) {
    __shared__ int   eL[MAXB];
    __shared__ float vL[MAXB];
    __shared__ int   cnt[128], sc[128], ofs[128];
    int k = blockIdx.x, t = threadIdx.x;
    int s = cbase[k];
    int e = cbase[k + 1];
    int n = e - s;
    if (t < 128) cnt[t] = 0;
    __syncthreads();
    for (int i = t; i < n; i += 256) {
        int   w = pk[s + i];
        float f = pv[s + i];
        if (i < MAXB) { eL[i] = w; vL[i] = f; }
        atomicAdd(&cnt[(w >> 18) & 127], 1);
    }
    __syncthreads();
    if (t < 128) sc[t] = cnt[t];
    __syncthreads();
    for (int off = 1; off < 128; off <<= 1) {
        int x = 0;
        if (t < 128) { x = sc[t]; if (t >= off) x += sc[t - off]; }
        __syncthreads();
        if (t < 128) sc[t] = x;
        __syncthreads();
    }
    if (t < 128) {
        int rs = sc[t] - cnt[t];             // exclusive start for row t
        ofs[t] = rs;
        int r = (k << 7) + t;
        if (r < NTOT) rowptr[r] = s + rs;
    }
    __syncthreads();
    for (int i = t; i < n; i += 256) {
        int w; float f;
        if (i < MAXB) { w = eL[i]; f = vL[i]; }
        else          { w = pk[s + i]; f = pv[s + i]; }   // overflow safety
        int r7 = (w >> 18) & 127;
        int p  = atomicAdd(&ofs[r7], 1);     // LDS atomic
        pcol[s + p] = w & 0x3FFFF;
        pval[s + p] = f;
    }
}

// ---------------- SpMM: 4 rows/wave, 16 lanes/row, float4 gather, 4-unroll ----

__global__ void spmm_csr_q_kernel(const int* __restrict__ rowptr,
                                  const int* __restrict__ pcol,
                                  const float* __restrict__ pval,
                                  const float4* __restrict__ cur4,
                                  float4* __restrict__ next4) {
    int t    = blockIdx.x * blockDim.x + threadIdx.x;
    int wid  = t >> 6;
    int lane = t & 63;
    int q    = lane >> 4;
    int li   = lane & 15;
    int r    = wid * 4 + q;
    if (r >= NTOT) return;
    int s = rowptr[r];
    int e = rowptr[r + 1];
    float4 a0 = make_float4(0.f, 0.f, 0.f, 0.f);
    float4 a1 = make_float4(0.f, 0.f, 0.f, 0.f);
    float4 a2 = make_float4(0.f, 0.f, 0.f, 0.f);
    float4 a3 = make_float4(0.f, 0.f, 0.f, 0.f);
    int k = s;
    for (; k + 4 <= e; k += 4) {
        int   c0 = pcol[k];
        int   c1 = pcol[k + 1];
        int   c2 = pcol[k + 2];
        int   c3 = pcol[k + 3];
        float v0 = pval[k];
        float v1 = pval[k + 1];
        float v2 = pval[k + 2];
        float v3 = pval[k + 3];
        float4 x0 = cur4[c0 * 16 + li];
        float4 x1 = cur4[c1 * 16 + li];
        float4 x2 = cur4[c2 * 16 + li];
        float4 x3 = cur4[c3 * 16 + li];
        a0.x += v0 * x0.x; a0.y += v0 * x0.y; a0.z += v0 * x0.z; a0.w += v0 * x0.w;
        a1.x += v1 * x1.x; a1.y += v1 * x1.y; a1.z += v1 * x1.z; a1.w += v1 * x1.w;
        a2.x += v2 * x2.x; a2.y += v2 * x2.y; a2.z += v2 * x2.z; a2.w += v2 * x2.w;
        a3.x += v3 * x3.x; a3.y += v3 * x3.y; a3.z += v3 * x3.z; a3.w += v3 * x3.w;
    }
    for (; k < e; ++k) {
        int   c0 = pcol[k];
        float v0 = pval[k];
        float4 x0 = cur4[c0 * 16 + li];
        a0.x += v0 * x0.x; a0.y += v0 * x0.y; a0.z += v0 * x0.z; a0.w += v0 * x0.w;
    }
    float4 o;
    o.x = (a0.x + a1.x) + (a2.x + a3.x);
    o.y = (a0.y + a1.y) + (a2.y + a3.y);
    o.z = (a0.z + a1.z) + (a2.z + a3.z);
    o.w = (a0.w + a1.w) + (a2.w + a3.w);
    next4[r * 16 + li] = o;
}

// layer-3 only at batch rows: 4 batch entries/wave, accumulate into ub/ib
__global__ void spmv_batch_kernel(const int* __restrict__ rowptr,
                                  const int* __restrict__ pcol,
                                  const float* __restrict__ pval,
                                  const int* __restrict__ batch,
                                  const float4* __restrict__ cur4,
                                  float4* __restrict__ ub4,
                                  float4* __restrict__ ib4) {
    int t    = blockIdx.x * blockDim.x + threadIdx.x;
    int wid  = t >> 6;
    int lane = t & 63;
    int q    = lane >> 4;
    int li   = lane & 15;
    int idx  = wid * 4 + q;           // 0..2*BATCH-1
    if (idx >= 2 * BATCH) return;
    int b = idx & (BATCH - 1);
    int r;
    float4* dst;
    if (idx < BATCH) { r = batch[2 * b];               dst = ub4; }
    else             { r = N_USERS + batch[2 * b + 1]; dst = ib4; }
    int s = rowptr[r];
    int e = rowptr[r + 1];
    float4 a0 = make_float4(0.f, 0.f, 0.f, 0.f);
    float4 a1 = make_float4(0.f, 0.f, 0.f, 0.f);
    float4 a2 = make_float4(0.f, 0.f, 0.f, 0.f);
    float4 a3 = make_float4(0.f, 0.f, 0.f, 0.f);
    int k = s;
    for (; k + 4 <= e; k += 4) {
        int   c0 = pcol[k];
        int   c1 = pcol[k + 1];
        int   c2 = pcol[k + 2];
        int   c3 = pcol[k + 3];
        float v0 = pval[k];
        float v1 = pval[k + 1];
        float v2 = pval[k + 2];
        float v3 = pval[k + 3];
        float4 x0 = cur4[c0 * 16 + li];
        float4 x1 = cur4[c1 * 16 + li];
        float4 x2 = cur4[c2 * 16 + li];
        float4 x3 = cur4[c3 * 16 + li];
        a0.x += v0 * x0.x; a0.y += v0 * x0.y; a0.z += v0 * x0.z; a0.w += v0 * x0.w;
        a1.x += v1 * x1.x; a1.y += v1 * x1.y; a1.z += v1 * x1.z; a1.w += v1 * x1.w;
        a2.x += v2 * x2.x; a2.y += v2 * x2.y; a2.z += v2 * x2.z; a2.w += v2 * x2.w;
        a3.x += v3 * x3.x; a3.y += v3 * x3.y; a3.z += v3 * x3.z; a3.w += v3 * x3.w;
    }
    for (; k < e; ++k) {
        int   c0 = pcol[k];
        float v0 = pval[k];
        float4 x0 = cur4[c0 * 16 + li];
        a0.x += v0 * x0.x; a0.y += v0 * x0.y; a0.z += v0 * x0.z; a0.w += v0 * x0.w;
    }
    float4 p = dst[b * 16 + li];
    p.x += (a0.x + a1.x) + (a2.x + a3.x);
    p.y += (a0.y + a1.y) + (a2.y + a3.y);
    p.z += (a0.z + a1.z) + (a2.z + a3.z);
    p.w += (a0.w + a1.w) + (a2.w + a3.w);
    dst[b * 16 + li] = p;
}

// ---------------- fallback atomic SpMM (small-ws path) ----------------

__global__ void spmm_atomic_kernel(const int* __restrict__ rows,
                                   const int* __restrict__ cols,
                                   const float* __restrict__ vals,
                                   const float* __restrict__ cur,
                                   float* __restrict__ next) {
    int t    = blockIdx.x * blockDim.x + threadIdx.x;
    int nz   = t >> 6;
    int lane = t & 63;
    if (nz >= NNZ) return;
    int   r = rows[nz];
    int   c = cols[nz];
    float v = vals[nz];
    float x = cur[(long)c * EMB + lane];
    atomicAdd(&next[(long)r * EMB + lane], v * x);
}

// ---------------- launch ----------------

extern "C" void kernel_launch(void* const* d_in, const int* in_sizes, int n_in,
                              void* d_out, int out_size, void* d_ws, size_t ws_size,
                              hipStream_t stream) {
    const float* ue    = (const float*)d_in[0];
    const float* ie    = (const float*)d_in[1];
    const int*   rows  = (const int*)d_in[2];
    const int*   cols  = (const int*)d_in[3];
    const float* vals  = (const float*)d_in[4];
    const int*   batch = (const int*)d_in[5];
    float*       out   = (float*)d_out;

    const size_t EMB_BYTES = (size_t)NTOT * EMB * sizeof(float);   // 64,000,000
    const size_t BUF_BYTES = (size_t)BATCH * EMB * sizeof(float);  // 4,194,304
    const size_t NZI_BYTES = (size_t)NNZ * sizeof(int);            // 20,000,000
    const size_t PTR_BYTES = ((size_t)(NTOT + 1) * sizeof(int) + 255) & ~(size_t)255;

    char* ws = (char*)d_ws;
    size_t off = 0;
    float* cur    = (float*)(ws + off); off += EMB_BYTES;
    float* nxt    = (float*)(ws + off); off += EMB_BYTES;
    float* ub     = (float*)(ws + off); off += BUF_BYTES;
    float* ib     = (float*)(ws + off); off += BUF_BYTES;   // ub,ib contiguous
    int*   pcol   = (int*)(ws + off);   off += NZI_BYTES;
    float* pval   = (float*)(ws + off); off += NZI_BYTES;
    int*   rowptr = (int*)(ws + off);   off += PTR_BYTES;
    const size_t NEEDED_CSR = off;

    // Build-time scratch ALIASED into nxt (dead before first spmm writes nxt):
    //   pk @ 0 (20 MB) ; pv @ 20 MB (20 MB) ; H @ 40 MB (10 MB) ; ctot/cbase after
    int*   pk    = (int*)((char*)nxt);
    float* pv    = (float*)((char*)nxt + NZI_BYTES);
    int*   H     = (int*)((char*)nxt + 2 * NZI_BYTES);
    int*   ctot  = (int*)((char*)nxt + 2 * NZI_BYTES + (size_t)NBLK_P * BPAD * 4 + 4096);
    int*   cbase = (int*)((char*)nxt + 2 * NZI_BYTES + (size_t)NBLK_P * BPAD * 4 + 20480);

    // 1) cur = concat(emb)
    {
        int n_t4 = NTOT * (EMB / 4);
        init_cur_kernel<<<(n_t4 + 255) / 256, 256, 0, stream>>>(ue, ie, cur);
    }
    // 2) layer-0 contribution at batch rows
    hipMemsetAsync(ub, 0, 2 * BUF_BYTES, stream);
    gather_add_kernel<<<(BATCH * 64) / 256, 256, 0, stream>>>(cur, batch, ub, ib);

    if (ws_size >= NEEDED_CSR) {
        // 3) atomic-free CSR build; partition scatter in TWO bucket-range passes
        part_hist_kernel<<<NBLK_P, 256, 0, stream>>>(rows, H);
        col_scan_kernel<<<NBUCK, 256, 0, stream>>>(H, ctot);
        bucket_scan_kernel<<<1, 256, 0, stream>>>(ctot, cbase, rowptr);
        part_scatter_kernel<<<NBLK_P, 256, 0, stream>>>(rows, cols, vals, H, cbase,
                                                        0, HBUCK, pk, pv);
        part_scatter_kernel<<<NBLK_P, 256, 0, stream>>>(rows, cols, vals, H, cbase,
                                                        HBUCK, NBUCK, pk, pv);
        bucket_sort_kernel<<<NBUCK, 256, 0, stream>>>(cbase, pk, pv, rowptr, pcol, pval);

        // 4) layers 1,2 full; layer 3 only at batch rows
        for (int l = 0; l < 2; ++l) {
            spmm_csr_q_kernel<<<(NTOT / 4 * 64) / 256, 256, 0, stream>>>(
                rowptr, pcol, pval, (const float4*)cur, (float4*)nxt);
            gather_add_kernel<<<(BATCH * 64) / 256, 256, 0, stream>>>(nxt, batch, ub, ib);
            float* tmp = cur; cur = nxt; nxt = tmp;
        }
        spmv_batch_kernel<<<(2 * BATCH / 4 * 64) / 256, 256, 0, stream>>>(
            rowptr, pcol, pval, batch, (const float4*)cur, (float4*)ub, (float4*)ib);
    } else {
        // fallback: atomic path (fits in 136.4 MB)
        for (int l = 0; l < 3; ++l) {
            hipMemsetAsync(nxt, 0, EMB_BYTES, stream);
            spmm_atomic_kernel<<<NNZ / 4, 256, 0, stream>>>(rows, cols, vals, cur, nxt);
            gather_add_kernel<<<(BATCH * 64) / 256, 256, 0, stream>>>(nxt, batch, ub, ib);
            float* tmp = cur; cur = nxt; nxt = tmp;
        }
    }

    // 5) score
    dot_kernel<<<(BATCH * 64) / 256, 256, 0, stream>>>(ub, ib, out);
}

// Round 8
// 652.756 us; speedup vs baseline: 5.2884x; 1.2952x over previous
//
#include <hip/hip_runtime.h>
#include <hip/hip_fp16.h>

#define N_USERS 200000
#define N_ITEMS 50000
#define NTOT    250000
#define NNZ     5000000
#define EMB     64
#define BATCH   16384

// ---- bucket-build parameters ----
#define EPB     4096                         // elements per partition block
#define NBLK_P  ((NNZ + EPB - 1) / EPB)      // 1221
#define NBUCK   ((NTOT + 127) >> 7)          // 1954 buckets of 128 rows
#define HBUCK   977                          // bucket-range split point
#define BPAD    2048                         // padded bucket stride in H
#define MAXB    3072                         // max bucket size (mean 2560)

// half4 loaded/stored as one float2 (8 B)
__device__ inline float4 h4_to_f4(float2 raw) {
    __half2 h01 = *(__half2*)&raw.x;
    __half2 h23 = *(__half2*)&raw.y;
    float2 f01 = __half22float2(h01);
    float2 f23 = __half22float2(h23);
    return make_float4(f01.x, f01.y, f23.x, f23.y);
}
__device__ inline float2 f4_to_h4(float4 v) {
    __half2 h01 = __floats2half2_rn(v.x, v.y);
    __half2 h23 = __floats2half2_rn(v.z, v.w);
    float2 raw;
    raw.x = *(float*)&h01;
    raw.y = *(float*)&h23;
    return raw;
}

// ---------------- common kernels ----------------

// cur_h = half(concat(user_emb, item_emb)); thread = 4 elems
__global__ void init_cur_h_kernel(const float4* __restrict__ ue4,
                                  const float4* __restrict__ ie4,
                                  float2* __restrict__ curh) {
    int i = blockIdx.x * blockDim.x + threadIdx.x;         // float4 index
    const int n_u4 = N_USERS * 16;                         // 3.2M
    const int n_t4 = NTOT * 16;                            // 4.0M
    if (i >= n_t4) return;
    float4 v = (i < n_u4) ? ue4[i] : ie4[i - n_u4];
    curh[i] = f4_to_h4(v);
}

// layer-0 term, exact fp32 straight from inputs (also initializes ub/ib)
__global__ void gather_emb_kernel(const float* __restrict__ ue,
                                  const float* __restrict__ ie,
                                  const int* __restrict__ batch,
                                  float* __restrict__ ub,
                                  float* __restrict__ ib) {
    int t    = blockIdx.x * blockDim.x + threadIdx.x;
    int b    = t >> 6;
    int lane = t & 63;
    if (b >= BATCH) return;
    int ur = batch[2 * b];
    int ir = batch[2 * b + 1];
    ub[(long)b * EMB + lane] = ue[(long)ur * EMB + lane];
    ib[(long)b * EMB + lane] = ie[(long)ir * EMB + lane];
}

// ub/ib += half src at batch rows (layers 1,2)
__global__ void gather_add_h_kernel(const __half* __restrict__ src,
                                    const int* __restrict__ batch,
                                    float* __restrict__ ub,
                                    float* __restrict__ ib) {
    int t    = blockIdx.x * blockDim.x + threadIdx.x;
    int b    = t >> 6;
    int lane = t & 63;
    if (b >= BATCH) return;
    int ur = batch[2 * b];
    int ir = N_USERS + batch[2 * b + 1];
    ub[(long)b * EMB + lane] += __half2float(src[(long)ur * EMB + lane]);
    ib[(long)b * EMB + lane] += __half2float(src[(long)ir * EMB + lane]);
}

__global__ void dot_kernel(const float* __restrict__ ub,
                           const float* __restrict__ ib,
                           float* __restrict__ out) {
    int t    = blockIdx.x * blockDim.x + threadIdx.x;
    int b    = t >> 6;
    int lane = t & 63;
    if (b >= BATCH) return;
    float p = ub[(long)b * EMB + lane] * ib[(long)b * EMB + lane];
    #pragma unroll
    for (int off = 32; off > 0; off >>= 1)
        p += __shfl_down(p, off, 64);
    if (lane == 0) out[b] = p * (1.0f / 16.0f);
}

// ---------------- atomic-free CSR build (unchanged from R7) ----------------

__global__ void part_hist_kernel(const int* __restrict__ rows, int* __restrict__ H) {
    __shared__ int h[BPAD];
    int b = blockIdx.x, t = threadIdx.x;
    for (int k = t; k < BPAD; k += 256) h[k] = 0;
    __syncthreads();
    int s = b * EPB;
    int e = s + EPB; if (e > NNZ) e = NNZ;
    for (int i = s + t; i < e; i += 256)
        atomicAdd(&h[rows[i] >> 7], 1);
    __syncthreads();
    for (int k = t; k < BPAD; k += 256) H[b * BPAD + k] = h[k];
}

__global__ void col_scan_kernel(int* __restrict__ H, int* __restrict__ ctot) {
    __shared__ int s[256];
    int k = blockIdx.x;
    int t = threadIdx.x;
    int v[5]; int tsum = 0;
    #pragma unroll
    for (int j = 0; j < 5; ++j) {
        int b = t * 5 + j;
        v[j] = (b < NBLK_P) ? H[b * BPAD + k] : 0;
        tsum += v[j];
    }
    s[t] = tsum;
    __syncthreads();
    for (int off = 1; off < 256; off <<= 1) {
        int x = s[t];
        int y = (t >= off) ? s[t - off] : 0;
        __syncthreads();
        s[t] = x + y;
        __syncthreads();
    }
    int run = (t == 0) ? 0 : s[t - 1];
    #pragma unroll
    for (int j = 0; j < 5; ++j) {
        int b = t * 5 + j;
        if (b < NBLK_P) { H[b * BPAD + k] = run; run += v[j]; }
    }
    if (t == 255) ctot[k] = s[255];
}

__global__ void bucket_scan_kernel(const int* __restrict__ ctot,
                                   int* __restrict__ cbase,
                                   int* __restrict__ rowptr) {
    __shared__ int s[256];
    int t = threadIdx.x;
    int v[8]; int tsum = 0;
    #pragma unroll
    for (int j = 0; j < 8; ++j) {
        int k = t * 8 + j;
        v[j] = (k < NBUCK) ? ctot[k] : 0;
        tsum += v[j];
    }
    s[t] = tsum;
    __syncthreads();
    for (int off = 1; off < 256; off <<= 1) {
        int x = s[t];
        int y = (t >= off) ? s[t - off] : 0;
        __syncthreads();
        s[t] = x + y;
        __syncthreads();
    }
    int run = (t == 0) ? 0 : s[t - 1];
    #pragma unroll
    for (int j = 0; j < 8; ++j) {
        int k = t * 8 + j;
        if (k < NBUCK)       { cbase[k] = run; run += v[j]; }
        else if (k == NBUCK) { cbase[k] = run; }
    }
    if (t == 0) rowptr[NTOT] = NNZ;
}

__global__ void part_scatter_kernel(const int* __restrict__ rows,
                                    const int* __restrict__ cols,
                                    const float* __restrict__ vals,
                                    const int* __restrict__ H,
                                    const int* __restrict__ cbase,
                                    int klo, int khi,
                                    int* __restrict__ pk,
                                    float* __restrict__ pv) {
    __shared__ int bb[1024];
    __shared__ int h2[1024];
    int b = blockIdx.x, t = threadIdx.x;
    int w = khi - klo;
    for (int k = t; k < 1024; k += 256) {
        int kk = klo + k;
        bb[k] = (k < w) ? (cbase[kk] + H[b * BPAD + kk]) : 0;
        h2[k] = 0;
    }
    __syncthreads();
    int s = b * EPB;
    int e = s + EPB; if (e > NNZ) e = NNZ;
    for (int i = s + t; i < e; i += 256) {
        int r = rows[i];
        int k = (r >> 7) - klo;
        if ((unsigned)k >= (unsigned)w) continue;
        int rank = atomicAdd(&h2[k], 1);
        int pos  = bb[k] + rank;
        pk[pos] = cols[i] | ((r & 127) << 18);
        pv[pos] = vals[i];
    }
}

__global__ void bucket_sort_kernel(const int* __restrict__ cbase,
                                   const int* __restrict__ pk,
                                   const float* __restrict__ pv,
                                   int* __restrict__ rowptr,
                                   int* __restrict__ pcol,
                                   float* __restrict__ pval) {
    __shared__ int   eL[MAXB];
    __shared__ float vL[MAXB];
    __shared__ int   cnt[128], sc[128], ofs[128];
    int k = blockIdx.x, t = threadIdx.x;
    int s = cbase[k];
    int e = cbase[k + 1];
    int n = e - s;
    if (t < 128) cnt[t] = 0;
    __syncthreads();
    for (int i = t; i < n; i += 256) {
        int   w = pk[s + i];
        float f = pv[s + i];
        if (i < MAXB) { eL[i] = w; vL[i] = f; }
        atomicAdd(&cnt[(w >> 18) & 127], 1);
    }
    __syncthreads();
    if (t < 128) sc[t] = cnt[t];
    __syncthreads();
    for (int off = 1; off < 128; off <<= 1) {
        int x = 0;
        if (t < 128) { x = sc[t]; if (t >= off) x += sc[t - off]; }
        __syncthreads();
        if (t < 128) sc[t] = x;
        __syncthreads();
    }
    if (t < 128) {
        int rs = sc[t] - cnt[t];
        ofs[t] = rs;
        int r = (k << 7) + t;
        if (r < NTOT) rowptr[r] = s + rs;
    }
    __syncthreads();
    for (int i = t; i < n; i += 256) {
        int w; float f;
        if (i < MAXB) { w = eL[i]; f = vL[i]; }
        else          { w = pk[s + i]; f = pv[s + i]; }
        int r7 = (w >> 18) & 127;
        int p  = atomicAdd(&ofs[r7], 1);
        pcol[s + p] = w & 0x3FFFF;
        pval[s + p] = f;
    }
}

// ---------------- SpMM (half): 4 rows/wave, 16 lanes/row, half4 gather -------

__global__ void spmm_csr_qh_kernel(const int* __restrict__ rowptr,
                                   const int* __restrict__ pcol,
                                   const float* __restrict__ pval,
                                   const float2* __restrict__ curh,
                                   float2* __restrict__ nexth) {
    int t    = blockIdx.x * blockDim.x + threadIdx.x;
    int wid  = t >> 6;
    int lane = t & 63;
    int q    = lane >> 4;
    int li   = lane & 15;
    int r    = wid * 4 + q;
    if (r >= NTOT) return;
    int s = rowptr[r];
    int e = rowptr[r + 1];
    float4 a0 = make_float4(0.f, 0.f, 0.f, 0.f);
    float4 a1 = make_float4(0.f, 0.f, 0.f, 0.f);
    float4 a2 = make_float4(0.f, 0.f, 0.f, 0.f);
    float4 a3 = make_float4(0.f, 0.f, 0.f, 0.f);
    int k = s;
    for (; k + 4 <= e; k += 4) {
        int   c0 = pcol[k];
        int   c1 = pcol[k + 1];
        int   c2 = pcol[k + 2];
        int   c3 = pcol[k + 3];
        float v0 = pval[k];
        float v1 = pval[k + 1];
        float v2 = pval[k + 2];
        float v3 = pval[k + 3];
        float4 x0 = h4_to_f4(curh[c0 * 16 + li]);
        float4 x1 = h4_to_f4(curh[c1 * 16 + li]);
        float4 x2 = h4_to_f4(curh[c2 * 16 + li]);
        float4 x3 = h4_to_f4(curh[c3 * 16 + li]);
        a0.x += v0 * x0.x; a0.y += v0 * x0.y; a0.z += v0 * x0.z; a0.w += v0 * x0.w;
        a1.x += v1 * x1.x; a1.y += v1 * x1.y; a1.z += v1 * x1.z; a1.w += v1 * x1.w;
        a2.x += v2 * x2.x; a2.y += v2 * x2.y; a2.z += v2 * x2.z; a2.w += v2 * x2.w;
        a3.x += v3 * x3.x; a3.y += v3 * x3.y; a3.z += v3 * x3.z; a3.w += v3 * x3.w;
    }
    for (; k < e; ++k) {
        int   c0 = pcol[k];
        float v0 = pval[k];
        float4 x0 = h4_to_f4(curh[c0 * 16 + li]);
        a0.x += v0 * x0.x; a0.y += v0 * x0.y; a0.z += v0 * x0.z; a0.w += v0 * x0.w;
    }
    float4 o;
    o.x = (a0.x + a1.x) + (a2.x + a3.x);
    o.y = (a0.y + a1.y) + (a2.y + a3.y);
    o.z = (a0.z + a1.z) + (a2.z + a3.z);
    o.w = (a0.w + a1.w) + (a2.w + a3.w);
    nexth[r * 16 + li] = f4_to_h4(o);
}

// layer-3 only at batch rows, accumulate fp32 into ub/ib
__global__ void spmv_batch_h_kernel(const int* __restrict__ rowptr,
                                    const int* __restrict__ pcol,
                                    const float* __restrict__ pval,
                                    const int* __restrict__ batch,
                                    const float2* __restrict__ curh,
                                    float4* __restrict__ ub4,
                                    float4* __restrict__ ib4) {
    int t    = blockIdx.x * blockDim.x + threadIdx.x;
    int wid  = t >> 6;
    int lane = t & 63;
    int q    = lane >> 4;
    int li   = lane & 15;
    int idx  = wid * 4 + q;
    if (idx >= 2 * BATCH) return;
    int b = idx & (BATCH - 1);
    int r;
    float4* dst;
    if (idx < BATCH) { r = batch[2 * b];               dst = ub4; }
    else             { r = N_USERS + batch[2 * b + 1]; dst = ib4; }
    int s = rowptr[r];
    int e = rowptr[r + 1];
    float4 a0 = make_float4(0.f, 0.f, 0.f, 0.f);
    float4 a1 = make_float4(0.f, 0.f, 0.f, 0.f);
    float4 a2 = make_float4(0.f, 0.f, 0.f, 0.f);
    float4 a3 = make_float4(0.f, 0.f, 0.f, 0.f);
    int k = s;
    for (; k + 4 <= e; k += 4) {
        int   c0 = pcol[k];
        int   c1 = pcol[k + 1];
        int   c2 = pcol[k + 2];
        int   c3 = pcol[k + 3];
        float v0 = pval[k];
        float v1 = pval[k + 1];
        float v2 = pval[k + 2];
        float v3 = pval[k + 3];
        float4 x0 = h4_to_f4(curh[c0 * 16 + li]);
        float4 x1 = h4_to_f4(curh[c1 * 16 + li]);
        float4 x2 = h4_to_f4(curh[c2 * 16 + li]);
        float4 x3 = h4_to_f4(curh[c3 * 16 + li]);
        a0.x += v0 * x0.x; a0.y += v0 * x0.y; a0.z += v0 * x0.z; a0.w += v0 * x0.w;
        a1.x += v1 * x1.x; a1.y += v1 * x1.y; a1.z += v1 * x1.z; a1.w += v1 * x1.w;
        a2.x += v2 * x2.x; a2.y += v2 * x2.y; a2.z += v2 * x2.z; a2.w += v2 * x2.w;
        a3.x += v3 * x3.x; a3.y += v3 * x3.y; a3.z += v3 * x3.z; a3.w += v3 * x3.w;
    }
    for (; k < e; ++k) {
        int   c0 = pcol[k];
        float v0 = pval[k];
        float4 x0 = h4_to_f4(curh[c0 * 16 + li]);
        a0.x += v0 * x0.x; a0.y += v0 * x0.y; a0.z += v0 * x0.z; a0.w += v0 * x0.w;
    }
    float4 p = dst[b * 16 + li];
    p.x += (a0.x + a1.x) + (a2.x + a3.x);
    p.y += (a0.y + a1.y) + (a2.y + a3.y);
    p.z += (a0.z + a1.z) + (a2.z + a3.z);
    p.w += (a0.w + a1.w) + (a2.w + a3.w);
    dst[b * 16 + li] = p;
}

// ---------------- fallback fp32 atomic path (small-ws) ----------------

__global__ void init_cur_kernel(const float* __restrict__ ue,
                                const float* __restrict__ ie,
                                float* __restrict__ cur) {
    long i = (long)blockIdx.x * blockDim.x + threadIdx.x;
    const long n_u4 = (long)N_USERS * EMB / 4;
    const long n_t4 = (long)NTOT * EMB / 4;
    if (i < n_u4) {
        ((float4*)cur)[i] = ((const float4*)ue)[i];
    } else if (i < n_t4) {
        ((float4*)cur)[i] = ((const float4*)ie)[i - n_u4];
    }
}

__global__ void gather_add_kernel(const float* __restrict__ src,
                                  const int* __restrict__ batch,
                                  float* __restrict__ ub,
                                  float* __restrict__ ib) {
    int t    = blockIdx.x * blockDim.x + threadIdx.x;
    int b    = t >> 6;
    int lane = t & 63;
    if (b >= BATCH) return;
    int ur = batch[2 * b];
    int ir = N_USERS + batch[2 * b + 1];
    ub[(long)b * EMB + lane] += src[(long)ur * EMB + lane];
    ib[(long)b * EMB + lane] += src[(long)ir * EMB + lane];
}

__global__ void spmm_atomic_kernel(const int* __restrict__ rows,
                                   const int* __restrict__ cols,
                                   const float* __restrict__ vals,
                                   const float* __restrict__ cur,
                                   float* __restrict__ next) {
    int t    = blockIdx.x * blockDim.x + threadIdx.x;
    int nz   = t >> 6;
    int lane = t & 63;
    if (nz >= NNZ) return;
    int   r = rows[nz];
    int   c = cols[nz];
    float v = vals[nz];
    float x = cur[(long)c * EMB + lane];
    atomicAdd(&next[(long)r * EMB + lane], v * x);
}

// ---------------- launch ----------------

extern "C" void kernel_launch(void* const* d_in, const int* in_sizes, int n_in,
                              void* d_out, int out_size, void* d_ws, size_t ws_size,
                              hipStream_t stream) {
    const float* ue    = (const float*)d_in[0];
    const float* ie    = (const float*)d_in[1];
    const int*   rows  = (const int*)d_in[2];
    const int*   cols  = (const int*)d_in[3];
    const float* vals  = (const float*)d_in[4];
    const int*   batch = (const int*)d_in[5];
    float*       out   = (float*)d_out;

    const size_t EMB_BYTES = (size_t)NTOT * EMB * sizeof(float);   // 64,000,000 (slot size)
    const size_t BUF_BYTES = (size_t)BATCH * EMB * sizeof(float);  // 4,194,304
    const size_t NZI_BYTES = (size_t)NNZ * sizeof(int);            // 20,000,000
    const size_t PTR_BYTES = ((size_t)(NTOT + 1) * sizeof(int) + 255) & ~(size_t)255;

    char* ws = (char*)d_ws;
    size_t off = 0;
    char*  slotA  = ws + off;           off += EMB_BYTES;   // fp32 cur OR half cur (32MB)
    char*  slotB  = ws + off;           off += EMB_BYTES;   // fp32 nxt OR half nxt + build scratch
    float* ub     = (float*)(ws + off); off += BUF_BYTES;
    float* ib     = (float*)(ws + off); off += BUF_BYTES;   // ub,ib contiguous
    int*   pcol   = (int*)(ws + off);   off += NZI_BYTES;
    float* pval   = (float*)(ws + off); off += NZI_BYTES;
    int*   rowptr = (int*)(ws + off);   off += PTR_BYTES;
    const size_t NEEDED_CSR = off;

    // Build scratch ALIASED into slotB (dead before first spmm writes nexth):
    int*   pk    = (int*)(slotB);
    float* pv    = (float*)(slotB + NZI_BYTES);
    int*   H     = (int*)(slotB + 2 * NZI_BYTES);
    int*   ctot  = (int*)(slotB + 2 * NZI_BYTES + (size_t)NBLK_P * BPAD * 4 + 4096);
    int*   cbase = (int*)(slotB + 2 * NZI_BYTES + (size_t)NBLK_P * BPAD * 4 + 20480);

    if (ws_size >= NEEDED_CSR) {
        float2* curh = (float2*)slotA;
        float2* nxth = (float2*)slotB;

        // 1) half cur = concat(emb); layer-0 term exact from fp32 inputs
        init_cur_h_kernel<<<(NTOT * 16 + 255) / 256, 256, 0, stream>>>(
            (const float4*)ue, (const float4*)ie, curh);
        gather_emb_kernel<<<(BATCH * 64) / 256, 256, 0, stream>>>(ue, ie, batch, ub, ib);

        // 2) atomic-free CSR build (scatter in two bucket-range passes)
        part_hist_kernel<<<NBLK_P, 256, 0, stream>>>(rows, H);
        col_scan_kernel<<<NBUCK, 256, 0, stream>>>(H, ctot);
        bucket_scan_kernel<<<1, 256, 0, stream>>>(ctot, cbase, rowptr);
        part_scatter_kernel<<<NBLK_P, 256, 0, stream>>>(rows, cols, vals, H, cbase,
                                                        0, HBUCK, pk, pv);
        part_scatter_kernel<<<NBLK_P, 256, 0, stream>>>(rows, cols, vals, H, cbase,
                                                        HBUCK, NBUCK, pk, pv);
        bucket_sort_kernel<<<NBUCK, 256, 0, stream>>>(cbase, pk, pv, rowptr, pcol, pval);

        // 3) layers 1,2 full (half); layer 3 only at batch rows
        for (int l = 0; l < 2; ++l) {
            spmm_csr_qh_kernel<<<(NTOT / 4 * 64) / 256, 256, 0, stream>>>(
                rowptr, pcol, pval, curh, nxth);
            gather_add_h_kernel<<<(BATCH * 64) / 256, 256, 0, stream>>>(
                (const __half*)nxth, batch, ub, ib);
            float2* tmp = curh; curh = nxth; nxth = tmp;
        }
        spmv_batch_h_kernel<<<(2 * BATCH / 4 * 64) / 256, 256, 0, stream>>>(
            rowptr, pcol, pval, batch, curh, (float4*)ub, (float4*)ib);
    } else {
        // fallback: fp32 atomic path
        float* cur = (float*)slotA;
        float* nxt = (float*)slotB;
        int n_t4 = NTOT * (EMB / 4);
        init_cur_kernel<<<(n_t4 + 255) / 256, 256, 0, stream>>>(ue, ie, cur);
        hipMemsetAsync(ub, 0, 2 * BUF_BYTES, stream);
        gather_add_kernel<<<(BATCH * 64) / 256, 256, 0, stream>>>(cur, batch, ub, ib);
        for (int l = 0; l < 3; ++l) {
            hipMemsetAsync(nxt, 0, EMB_BYTES, stream);
            spmm_atomic_kernel<<<NNZ / 4, 256, 0, stream>>>(rows, cols, vals, cur, nxt);
            gather_add_kernel<<<(BATCH * 64) / 256, 256, 0, stream>>>(nxt, batch, ub, ib);
            float* tmp = cur; cur = nxt; nxt = tmp;
        }
    }

    // 4) score
    dot_kernel<<<(BATCH * 64) / 256, 256, 0, stream>>>(ub, ib, out);
}

// Round 9
// 595.091 us; speedup vs baseline: 5.8008x; 1.0969x over previous
//
#include <hip/hip_runtime.h>
#include <hip/hip_fp16.h>

#define N_USERS 200000
#define N_ITEMS 50000
#define NTOT    250000
#define NNZ     5000000
#define EMB     64
#define BATCH   16384

// ---- two-phase radix build parameters ----
#define EPB     4096                         // elements per partition block
#define NBLK_P  ((NNZ + EPB - 1) / EPB)      // 1221
#define CB      128                          // coarse buckets: row>>11 (2048 rows; ids 0..122)
#define FPB     16                           // fine buckets per coarse (2048/128)
#define NFINE   (CB * FPB)                   // 2048 fine buckets of 128 rows
#define CH_MAX  12                           // max 4096-chunks per coarse (mean count 40960, +40 sigma)
#define MAXB    3072                         // max fine-bucket size (mean 2560)

// half4 loaded/stored as one float2 (8 B)
__device__ inline float4 h4_to_f4(float2 raw) {
    __half2 h01 = *(__half2*)&raw.x;
    __half2 h23 = *(__half2*)&raw.y;
    float2 f01 = __half22float2(h01);
    float2 f23 = __half22float2(h23);
    return make_float4(f01.x, f01.y, f23.x, f23.y);
}
__device__ inline float2 f4_to_h4(float4 v) {
    __half2 h01 = __floats2half2_rn(v.x, v.y);
    __half2 h23 = __floats2half2_rn(v.z, v.w);
    float2 raw;
    raw.x = *(float*)&h01;
    raw.y = *(float*)&h23;
    return raw;
}

// ---------------- common kernels ----------------

__global__ void init_cur_h_kernel(const float4* __restrict__ ue4,
                                  const float4* __restrict__ ie4,
                                  float2* __restrict__ curh) {
    int i = blockIdx.x * blockDim.x + threadIdx.x;         // float4 index
    const int n_u4 = N_USERS * 16;
    const int n_t4 = NTOT * 16;
    if (i >= n_t4) return;
    float4 v = (i < n_u4) ? ue4[i] : ie4[i - n_u4];
    curh[i] = f4_to_h4(v);
}

// layer-0 term, exact fp32 straight from inputs (also initializes ub/ib)
__global__ void gather_emb_kernel(const float* __restrict__ ue,
                                  const float* __restrict__ ie,
                                  const int* __restrict__ batch,
                                  float* __restrict__ ub,
                                  float* __restrict__ ib) {
    int t    = blockIdx.x * blockDim.x + threadIdx.x;
    int b    = t >> 6;
    int lane = t & 63;
    if (b >= BATCH) return;
    int ur = batch[2 * b];
    int ir = batch[2 * b + 1];
    ub[(long)b * EMB + lane] = ue[(long)ur * EMB + lane];
    ib[(long)b * EMB + lane] = ie[(long)ir * EMB + lane];
}

__global__ void gather_add_h_kernel(const __half* __restrict__ src,
                                    const int* __restrict__ batch,
                                    float* __restrict__ ub,
                                    float* __restrict__ ib) {
    int t    = blockIdx.x * blockDim.x + threadIdx.x;
    int b    = t >> 6;
    int lane = t & 63;
    if (b >= BATCH) return;
    int ur = batch[2 * b];
    int ir = N_USERS + batch[2 * b + 1];
    ub[(long)b * EMB + lane] += __half2float(src[(long)ur * EMB + lane]);
    ib[(long)b * EMB + lane] += __half2float(src[(long)ir * EMB + lane]);
}

__global__ void dot_kernel(const float* __restrict__ ub,
                           const float* __restrict__ ib,
                           float* __restrict__ out) {
    int t    = blockIdx.x * blockDim.x + threadIdx.x;
    int b    = t >> 6;
    int lane = t & 63;
    if (b >= BATCH) return;
    float p = ub[(long)b * EMB + lane] * ib[(long)b * EMB + lane];
    #pragma unroll
    for (int off = 32; off > 0; off >>= 1)
        p += __shfl_down(p, off, 64);
    if (lane == 0) out[b] = p * (1.0f / 16.0f);
}

// ---------------- atomic-free two-phase radix CSR build ----------------

// A1: per-block LDS histogram over 128 coarse buckets
__global__ void histA_kernel(const int* __restrict__ rows, int* __restrict__ H1) {
    __shared__ int h[CB];
    int b = blockIdx.x, t = threadIdx.x;
    if (t < CB) h[t] = 0;
    __syncthreads();
    int s = b * EPB;
    int e = s + EPB; if (e > NNZ) e = NNZ;
    for (int i = s + t; i < e; i += 256)
        atomicAdd(&h[rows[i] >> 11], 1);
    __syncthreads();
    if (t < CB) H1[b * CB + t] = h[t];
}

// A2: exclusive scan of each H1 column (over blocks); ctot1[k] = column sum
__global__ void col_scanA_kernel(int* __restrict__ H1, int* __restrict__ ctot1) {
    __shared__ int s[256];
    int k = blockIdx.x;       // coarse bucket
    int t = threadIdx.x;
    int v[5]; int tsum = 0;
    #pragma unroll
    for (int j = 0; j < 5; ++j) {
        int b = t * 5 + j;
        v[j] = (b < NBLK_P) ? H1[b * CB + k] : 0;
        tsum += v[j];
    }
    s[t] = tsum;
    __syncthreads();
    for (int off = 1; off < 256; off <<= 1) {
        int x = s[t];
        int y = (t >= off) ? s[t - off] : 0;
        __syncthreads();
        s[t] = x + y;
        __syncthreads();
    }
    int run = (t == 0) ? 0 : s[t - 1];
    #pragma unroll
    for (int j = 0; j < 5; ++j) {
        int b = t * 5 + j;
        if (b < NBLK_P) { H1[b * CB + k] = run; run += v[j]; }
    }
    if (t == 255) ctot1[k] = s[255];
}

// A3: exclusive scan over coarse totals -> cbase1[0..CB]; also rowptr[NTOT]=NNZ
__global__ void scanA_kernel(const int* __restrict__ ctot1,
                             int* __restrict__ cbase1,
                             int* __restrict__ rowptr) {
    __shared__ int s[256];
    int t = threadIdx.x;
    int v = (t < CB) ? ctot1[t] : 0;
    s[t] = v;
    __syncthreads();
    for (int off = 1; off < 256; off <<= 1) {
        int x = s[t];
        int y = (t >= off) ? s[t - off] : 0;
        __syncthreads();
        s[t] = x + y;
        __syncthreads();
    }
    if (t < CB) cbase1[t] = s[t] - v;
    if (t == 0) { cbase1[CB] = NNZ; rowptr[NTOT] = NNZ; }
}

// A4: coarse scatter. Runs of ~32 contiguous elems per (block,coarse) -> line-friendly.
// pack: col (18b) | row&0x7FF (11b) << 18
__global__ void scatterA_kernel(const int* __restrict__ rows,
                                const int* __restrict__ cols,
                                const float* __restrict__ vals,
                                const int* __restrict__ H1,
                                const int* __restrict__ cbase1,
                                int* __restrict__ pk1,
                                float* __restrict__ pv1) {
    __shared__ int bb[CB], h[CB];
    int b = blockIdx.x, t = threadIdx.x;
    if (t < CB) { bb[t] = cbase1[t] + H1[b * CB + t]; h[t] = 0; }
    __syncthreads();
    int s = b * EPB;
    int e = s + EPB; if (e > NNZ) e = NNZ;
    for (int i = s + t; i < e; i += 256) {
        int r = rows[i];
        int k = r >> 11;
        int rank = atomicAdd(&h[k], 1);      // LDS atomic
        int pos  = bb[k] + rank;
        pk1[pos] = cols[i] | ((r & 0x7FF) << 18);
        pv1[pos] = vals[i];
    }
}

// B1: per-(coarse,chunk) LDS histogram over 16 fine buckets
__global__ void histB_kernel(const int* __restrict__ pk1,
                             const int* __restrict__ cbase1,
                             int* __restrict__ H2) {
    __shared__ int h[FPB];
    int bid = blockIdx.x;                    // c*CH_MAX + j
    int c = bid / CH_MAX, j = bid % CH_MAX;
    int t = threadIdx.x;
    if (t < FPB) h[t] = 0;
    __syncthreads();
    int cs = cbase1[c], ce = cbase1[c + 1];
    int s = cs + j * EPB;
    int e = s + EPB; if (e > ce) e = ce;
    for (int i = s + t; i < e; i += 256)
        atomicAdd(&h[(pk1[i] >> 25) & 15], 1);
    __syncthreads();
    if (t < FPB) H2[bid * FPB + t] = h[t];
}

// B2: per coarse: chunk-scan + fine-scan -> H2 holds global bases; cbase2 = fine bases
__global__ void scanB_kernel(const int* __restrict__ cbase1,
                             int* __restrict__ H2,
                             int* __restrict__ cbase2) {
    __shared__ int tot[FPB], fb[FPB];
    int c = blockIdx.x, t = threadIdx.x;
    if (t < FPB) {
        int run = 0;
        for (int j = 0; j < CH_MAX; ++j) {
            int idx = (c * CH_MAX + j) * FPB + t;
            int tmp = H2[idx]; H2[idx] = run; run += tmp;
        }
        tot[t] = run;
    }
    __syncthreads();
    if (t == 0) {
        int run = cbase1[c];
        for (int k = 0; k < FPB; ++k) { fb[k] = run; run += tot[k]; }
    }
    __syncthreads();
    if (t < FPB) {
        cbase2[c * FPB + t] = fb[t];
        for (int j = 0; j < CH_MAX; ++j)
            H2[(c * CH_MAX + j) * FPB + t] += fb[t];
    }
    if (c == CB - 1 && t == 0) cbase2[NFINE] = NNZ;
}

// B3: fine scatter within coarse regions. Runs of ~256 contiguous elems.
__global__ void scatterB_kernel(const int* __restrict__ pk1,
                                const float* __restrict__ pv1,
                                const int* __restrict__ cbase1,
                                const int* __restrict__ H2,
                                int* __restrict__ pk2,
                                float* __restrict__ pv2) {
    __shared__ int bb[FPB], h[FPB];
    int bid = blockIdx.x;
    int c = bid / CH_MAX, j = bid % CH_MAX;
    int t = threadIdx.x;
    if (t < FPB) { bb[t] = H2[bid * FPB + t]; h[t] = 0; }
    __syncthreads();
    int cs = cbase1[c], ce = cbase1[c + 1];
    int s = cs + j * EPB;
    int e = s + EPB; if (e > ce) e = ce;
    for (int i = s + t; i < e; i += 256) {
        int   w = pk1[i];
        float f = pv1[i];
        int k = (w >> 25) & 15;
        int rank = atomicAdd(&h[k], 1);      // LDS atomic
        int pos  = bb[k] + rank;
        pk2[pos] = w;
        pv2[pos] = f;
    }
}

// C: one block per fine bucket: LDS counting sort over 128 rows -> rowptr + final CSR
__global__ void bucket_sort_kernel(const int* __restrict__ cbase2,
                                   const int* __restrict__ pk2,
                                   const float* __restrict__ pv2,
                                   int* __restrict__ rowptr,
                                   int* __restrict__ pcol,
                                   float* __restrict__ pval) {
    __shared__ int   eL[MAXB];
    __shared__ float vL[MAXB];
    __shared__ int   cnt[128], sc[128], ofs[128];
    int g = blockIdx.x, t = threadIdx.x;
    int s = cbase2[g];
    int e = cbase2[g + 1];
    int n = e - s;
    if (t < 128) cnt[t] = 0;
    __syncthreads();
    for (int i = t; i < n; i += 256) {
        int   w = pk2[s + i];
        float f = pv2[s + i];
        if (i < MAXB) { eL[i] = w; vL[i] = f; }
        atomicAdd(&cnt[(w >> 18) & 127], 1);
    }
    __syncthreads();
    if (t < 128) sc[t] = cnt[t];
    __syncthreads();
    for (int off = 1; off < 128; off <<= 1) {
        int x = 0;
        if (t < 128) { x = sc[t]; if (t >= off) x += sc[t - off]; }
        __syncthreads();
        if (t < 128) sc[t] = x;
        __syncthreads();
    }
    if (t < 128) {
        int rs = sc[t] - cnt[t];
        ofs[t] = rs;
        int r = (g << 7) + t;
        if (r < NTOT) rowptr[r] = s + rs;
    }
    __syncthreads();
    for (int i = t; i < n; i += 256) {
        int w; float f;
        if (i < MAXB) { w = eL[i]; f = vL[i]; }
        else          { w = pk2[s + i]; f = pv2[s + i]; }
        int r7 = (w >> 18) & 127;
        int p  = atomicAdd(&ofs[r7], 1);     // LDS atomic
        pcol[s + p] = w & 0x3FFFF;
        pval[s + p] = f;
    }
}

// ---------------- SpMM (half): 4 rows/wave, 16 lanes/row, half4 gather -------

__global__ void spmm_csr_qh_kernel(const int* __restrict__ rowptr,
                                   const int* __restrict__ pcol,
                                   const float* __restrict__ pval,
                                   const float2* __restrict__ curh,
                                   float2* __restrict__ nexth) {
    int t    = blockIdx.x * blockDim.x + threadIdx.x;
    int wid  = t >> 6;
    int lane = t & 63;
    int q    = lane >> 4;
    int li   = lane & 15;
    int r    = wid * 4 + q;
    if (r >= NTOT) return;
    int s = rowptr[r];
    int e = rowptr[r + 1];
    float4 a0 = make_float4(0.f, 0.f, 0.f, 0.f);
    float4 a1 = make_float4(0.f, 0.f, 0.f, 0.f);
    float4 a2 = make_float4(0.f, 0.f, 0.f, 0.f);
    float4 a3 = make_float4(0.f, 0.f, 0.f, 0.f);
    int k = s;
    for (; k + 4 <= e; k += 4) {
        int   c0 = pcol[k];
        int   c1 = pcol[k + 1];
        int   c2 = pcol[k + 2];
        int   c3 = pcol[k + 3];
        float v0 = pval[k];
        float v1 = pval[k + 1];
        float v2 = pval[k + 2];
        float v3 = pval[k + 3];
        float4 x0 = h4_to_f4(curh[c0 * 16 + li]);
        float4 x1 = h4_to_f4(curh[c1 * 16 + li]);
        float4 x2 = h4_to_f4(curh[c2 * 16 + li]);
        float4 x3 = h4_to_f4(curh[c3 * 16 + li]);
        a0.x += v0 * x0.x; a0.y += v0 * x0.y; a0.z += v0 * x0.z; a0.w += v0 * x0.w;
        a1.x += v1 * x1.x; a1.y += v1 * x1.y; a1.z += v1 * x1.z; a1.w += v1 * x1.w;
        a2.x += v2 * x2.x; a2.y += v2 * x2.y; a2.z += v2 * x2.z; a2.w += v2 * x2.w;
        a3.x += v3 * x3.x; a3.y += v3 * x3.y; a3.z += v3 * x3.z; a3.w += v3 * x3.w;
    }
    for (; k < e; ++k) {
        int   c0 = pcol[k];
        float v0 = pval[k];
        float4 x0 = h4_to_f4(curh[c0 * 16 + li]);
        a0.x += v0 * x0.x; a0.y += v0 * x0.y; a0.z += v0 * x0.z; a0.w += v0 * x0.w;
    }
    float4 o;
    o.x = (a0.x + a1.x) + (a2.x + a3.x);
    o.y = (a0.y + a1.y) + (a2.y + a3.y);
    o.z = (a0.z + a1.z) + (a2.z + a3.z);
    o.w = (a0.w + a1.w) + (a2.w + a3.w);
    nexth[r * 16 + li] = f4_to_h4(o);
}

__global__ void spmv_batch_h_kernel(const int* __restrict__ rowptr,
                                    const int* __restrict__ pcol,
                                    const float* __restrict__ pval,
                                    const int* __restrict__ batch,
                                    const float2* __restrict__ curh,
                                    float4* __restrict__ ub4,
                                    float4* __restrict__ ib4) {
    int t    = blockIdx.x * blockDim.x + threadIdx.x;
    int wid  = t >> 6;
    int lane = t & 63;
    int q    = lane >> 4;
    int li   = lane & 15;
    int idx  = wid * 4 + q;
    if (idx >= 2 * BATCH) return;
    int b = idx & (BATCH - 1);
    int r;
    float4* dst;
    if (idx < BATCH) { r = batch[2 * b];               dst = ub4; }
    else             { r = N_USERS + batch[2 * b + 1]; dst = ib4; }
    int s = rowptr[r];
    int e = rowptr[r + 1];
    float4 a0 = make_float4(0.f, 0.f, 0.f, 0.f);
    float4 a1 = make_float4(0.f, 0.f, 0.f, 0.f);
    float4 a2 = make_float4(0.f, 0.f, 0.f, 0.f);
    float4 a3 = make_float4(0.f, 0.f, 0.f, 0.f);
    int k = s;
    for (; k + 4 <= e; k += 4) {
        int   c0 = pcol[k];
        int   c1 = pcol[k + 1];
        int   c2 = pcol[k + 2];
        int   c3 = pcol[k + 3];
        float v0 = pval[k];
        float v1 = pval[k + 1];
        float v2 = pval[k + 2];
        float v3 = pval[k + 3];
        float4 x0 = h4_to_f4(curh[c0 * 16 + li]);
        float4 x1 = h4_to_f4(curh[c1 * 16 + li]);
        float4 x2 = h4_to_f4(curh[c2 * 16 + li]);
        float4 x3 = h4_to_f4(curh[c3 * 16 + li]);
        a0.x += v0 * x0.x; a0.y += v0 * x0.y; a0.z += v0 * x0.z; a0.w += v0 * x0.w;
        a1.x += v1 * x1.x; a1.y += v1 * x1.y; a1.z += v1 * x1.z; a1.w += v1 * x1.w;
        a2.x += v2 * x2.x; a2.y += v2 * x2.y; a2.z += v2 * x2.z; a2.w += v2 * x2.w;
        a3.x += v3 * x3.x; a3.y += v3 * x3.y; a3.z += v3 * x3.z; a3.w += v3 * x3.w;
    }
    for (; k < e; ++k) {
        int   c0 = pcol[k];
        float v0 = pval[k];
        float4 x0 = h4_to_f4(curh[c0 * 16 + li]);
        a0.x += v0 * x0.x; a0.y += v0 * x0.y; a0.z += v0 * x0.z; a0.w += v0 * x0.w;
    }
    float4 p = dst[b * 16 + li];
    p.x += (a0.x + a1.x) + (a2.x + a3.x);
    p.y += (a0.y + a1.y) + (a2.y + a3.y);
    p.z += (a0.z + a1.z) + (a2.z + a3.z);
    p.w += (a0.w + a1.w) + (a2.w + a3.w);
    dst[b * 16 + li] = p;
}

// ---------------- fallback fp32 atomic path (small-ws) ----------------

__global__ void init_cur_kernel(const float* __restrict__ ue,
                                const float* __restrict__ ie,
                                float* __restrict__ cur) {
    long i = (long)blockIdx.x * blockDim.x + threadIdx.x;
    const long n_u4 = (long)N_USERS * EMB / 4;
    const long n_t4 = (long)NTOT * EMB / 4;
    if (i < n_u4) {
        ((float4*)cur)[i] = ((const float4*)ue)[i];
    } else if (i < n_t4) {
        ((float4*)cur)[i] = ((const float4*)ie)[i - n_u4];
    }
}

__global__ void gather_add_kernel(const float* __restrict__ src,
                                  const int* __restrict__ batch,
                                  float* __restrict__ ub,
                                  float* __restrict__ ib) {
    int t    = blockIdx.x * blockDim.x + threadIdx.x;
    int b    = t >> 6;
    int lane = t & 63;
    if (b >= BATCH) return;
    int ur = batch[2 * b];
    int ir = N_USERS + batch[2 * b + 1];
    ub[(long)b * EMB + lane] += src[(long)ur * EMB + lane];
    ib[(long)b * EMB + lane] += src[(long)ir * EMB + lane];
}

__global__ void spmm_atomic_kernel(const int* __restrict__ rows,
                                   const int* __restrict__ cols,
                                   const float* __restrict__ vals,
                                   const float* __restrict__ cur,
                                   float* __restrict__ next) {
    int t    = blockIdx.x * blockDim.x + threadIdx.x;
    int nz   = t >> 6;
    int lane = t & 63;
    if (nz >= NNZ) return;
    int   r = rows[nz];
    int   c = cols[nz];
    float v = vals[nz];
    float x = cur[(long)c * EMB + lane];
    atomicAdd(&next[(long)r * EMB + lane], v * x);
}

// ---------------- launch ----------------

extern "C" void kernel_launch(void* const* d_in, const int* in_sizes, int n_in,
                              void* d_out, int out_size, void* d_ws, size_t ws_size,
                              hipStream_t stream) {
    const float* ue    = (const float*)d_in[0];
    const float* ie    = (const float*)d_in[1];
    const int*   rows  = (const int*)d_in[2];
    const int*   cols  = (const int*)d_in[3];
    const float* vals  = (const float*)d_in[4];
    const int*   batch = (const int*)d_in[5];
    float*       out   = (float*)d_out;

    const size_t HEMB_BYTES = (size_t)NTOT * EMB * sizeof(__half);  // 32,000,000
    const size_t BUF_BYTES  = (size_t)BATCH * EMB * sizeof(float);  // 4,194,304
    const size_t NZI_BYTES  = (size_t)NNZ * sizeof(int);            // 20,000,000
    const size_t PTR_BYTES  = ((size_t)(NTOT + 1) * sizeof(int) + 255) & ~(size_t)255;
    const size_t H1_BYTES   = ((size_t)NBLK_P * CB * sizeof(int) + 255) & ~(size_t)255;
    const size_t H2_BYTES   = ((size_t)CB * CH_MAX * FPB * sizeof(int) + 255) & ~(size_t)255;
    const size_t SB_BYTES   = 16384;  // ctot1 + cbase1 + cbase2 region

    char* ws = (char*)d_ws;
    size_t off = 0;
    float2* curh  = (float2*)(ws + off); off += HEMB_BYTES;
    float2* nxth  = (float2*)(ws + off); off += HEMB_BYTES;
    float*  ub    = (float*)(ws + off);  off += BUF_BYTES;
    float*  ib    = (float*)(ws + off);  off += BUF_BYTES;   // ub,ib contiguous
    int*    bufAk = (int*)(ws + off);    off += NZI_BYTES;   // scatterA out -> final pcol
    float*  bufAv = (float*)(ws + off);  off += NZI_BYTES;   // scatterA out -> final pval
    int*    bufBk = (int*)(ws + off);    off += NZI_BYTES;   // scatterB out, sort in
    float*  bufBv = (float*)(ws + off);  off += NZI_BYTES;
    int*    rowptr= (int*)(ws + off);    off += PTR_BYTES;
    int*    H1    = (int*)(ws + off);    off += H1_BYTES;
    int*    H2    = (int*)(ws + off);    off += H2_BYTES;
    int*    ctot1 = (int*)(ws + off);
    int*    cbase1= ctot1 + 1024;
    int*    cbase2= ctot1 + 2048;        off += SB_BYTES;
    const size_t NEEDED_CSR = off;       // ~154 MB

    if (ws_size >= NEEDED_CSR) {
        // 1) half cur = concat(emb); layer-0 term exact from fp32 inputs
        init_cur_h_kernel<<<(NTOT * 16 + 255) / 256, 256, 0, stream>>>(
            (const float4*)ue, (const float4*)ie, curh);
        gather_emb_kernel<<<(BATCH * 64) / 256, 256, 0, stream>>>(ue, ie, batch, ub, ib);

        // 2) two-phase radix CSR build (contiguous-run scatters, no global atomics)
        histA_kernel<<<NBLK_P, 256, 0, stream>>>(rows, H1);
        col_scanA_kernel<<<CB, 256, 0, stream>>>(H1, ctot1);
        scanA_kernel<<<1, 256, 0, stream>>>(ctot1, cbase1, rowptr);
        scatterA_kernel<<<NBLK_P, 256, 0, stream>>>(rows, cols, vals, H1, cbase1,
                                                    bufAk, bufAv);
        histB_kernel<<<CB * CH_MAX, 256, 0, stream>>>(bufAk, cbase1, H2);
        scanB_kernel<<<CB, 64, 0, stream>>>(cbase1, H2, cbase2);
        scatterB_kernel<<<CB * CH_MAX, 256, 0, stream>>>(bufAk, bufAv, cbase1, H2,
                                                         bufBk, bufBv);
        bucket_sort_kernel<<<NFINE, 256, 0, stream>>>(cbase2, bufBk, bufBv,
                                                      rowptr, bufAk, bufAv);
        int* pcolF  = bufAk;   // final CSR
        float* pvalF= bufAv;

        // 3) layers 1,2 full (half); layer 3 only at batch rows
        float2* c = curh; float2* n = nxth;
        for (int l = 0; l < 2; ++l) {
            spmm_csr_qh_kernel<<<(NTOT / 4 * 64) / 256, 256, 0, stream>>>(
                rowptr, pcolF, pvalF, c, n);
            gather_add_h_kernel<<<(BATCH * 64) / 256, 256, 0, stream>>>(
                (const __half*)n, batch, ub, ib);
            float2* tmp = c; c = n; n = tmp;
        }
        spmv_batch_h_kernel<<<(2 * BATCH / 4 * 64) / 256, 256, 0, stream>>>(
            rowptr, pcolF, pvalF, batch, c, (float4*)ub, (float4*)ib);
    } else {
        // fallback: fp32 atomic path (independent layout, 136.4 MB)
        const size_t EMB_BYTES = (size_t)NTOT * EMB * sizeof(float);
        float* cur = (float*)ws;
        float* nxt = (float*)(ws + EMB_BYTES);
        float* ub2 = (float*)(ws + 2 * EMB_BYTES);
        float* ib2 = (float*)(ws + 2 * EMB_BYTES + BUF_BYTES);
        int n_t4 = NTOT * (EMB / 4);
        init_cur_kernel<<<(n_t4 + 255) / 256, 256, 0, stream>>>(ue, ie, cur);
        hipMemsetAsync(ub2, 0, 2 * BUF_BYTES, stream);
        gather_add_kernel<<<(BATCH * 64) / 256, 256, 0, stream>>>(cur, batch, ub2, ib2);
        for (int l = 0; l < 3; ++l) {
            hipMemsetAsync(nxt, 0, EMB_BYTES, stream);
            spmm_atomic_kernel<<<NNZ / 4, 256, 0, stream>>>(rows, cols, vals, cur, nxt);
            gather_add_kernel<<<(BATCH * 64) / 256, 256, 0, stream>>>(nxt, batch, ub2, ib2);
            float* tmp = cur; cur = nxt; nxt = tmp;
        }
        dot_kernel<<<(BATCH * 64) / 256, 256, 0, stream>>>(ub2, ib2, out);
        return;
    }

    // 4) score
    dot_kernel<<<(BATCH * 64) / 256, 256, 0, stream>>>(ub, ib, out);
}